// Round 11
// baseline (233.794 us; speedup 1.0000x reference)
//
#include <hip/hip_runtime.h>
#include <hip/hip_bf16.h>

#define W_WORDS 2048
#define H_DIM   1024
#define C_LAB   32
#define HID_D   512
#define MAXW    12
#define NSPAN   (W_WORDS * MAXW)

typedef __attribute__((ext_vector_type(8))) short bf16x8;
typedef __attribute__((ext_vector_type(4))) float f32x4;

__device__ __forceinline__ unsigned short f2b(float x) {
  union { float f; unsigned int i; } v; v.f = x;
  unsigned int r = v.i + 0x7FFFu + ((v.i >> 16) & 1u);
  return (unsigned short)(r >> 16);
}
__device__ __forceinline__ float b2f(unsigned short b) {
  union { float f; unsigned int i; } v; v.i = ((unsigned int)b) << 16;
  return v.f;
}

#define GLOAD_LDS16(g, l)                                                    \
  __builtin_amdgcn_global_load_lds(                                          \
      (const __attribute__((address_space(1))) unsigned int*)(g),            \
      (__attribute__((address_space(3))) unsigned int*)(l), 16, 0, 0)

// ---------- mega0: 6 transposes (z<6) + gather (z==6) + Wtb0 cvt (z==7) ----------
__global__ void mega0_k(const float* __restrict__ hs, const int* __restrict__ wm,
    unsigned short* __restrict__ we_b,
    const float* __restrict__ Wt, const float* __restrict__ W1a,
    const float* __restrict__ Wsp1, const float* __restrict__ W1c,
    const float* __restrict__ Wsp2,
    unsigned short* __restrict__ WtT, unsigned short* __restrict__ W1aT,
    unsigned short* __restrict__ Wsp1Tc, float* __restrict__ W1cT,
    float* __restrict__ Wsp2T, unsigned short* __restrict__ Wtb0) {
  if (blockIdx.z == 6) {  // gather: we_b[m-1] = bf16(hs[t])
    int t = blockIdx.y * 96 + blockIdx.x;
    int m = wm[t];
    if (m <= 0) return;
    const float* src = hs + (size_t)t * H_DIM;
    unsigned short* dst = we_b + (size_t)(m - 1) * H_DIM;
    int i = (threadIdx.y * 32 + threadIdx.x) * 4;
    float4 v = *(const float4*)(src + i);
    *(ushort4*)(dst + i) = make_ushort4(f2b(v.x), f2b(v.y), f2b(v.z), f2b(v.w));
    return;
  }
  int c0 = blockIdx.x * 32, r0 = blockIdx.y * 32;
  if (blockIdx.z == 7) {  // Wtb0[h][g] = bf16(Wt[h][g]), g<1024
    if (c0 >= 1024) return;
    for (int i = threadIdx.y; i < 32; i += 8)
      Wtb0[(size_t)(r0 + i) * 1024 + c0 + threadIdx.x] =
          f2b(Wt[(size_t)(r0 + i) * 2048 + c0 + threadIdx.x]);
    return;
  }
  const float* in;
  void* out;
  int R, C, obf;
  switch (blockIdx.z) {
    case 0: in = Wt;   out = WtT;    R = 1024; C = 2048; obf = 1; break;
    case 1: in = W1a;  out = W1aT;   R = 1024; C = 512;  obf = 1; break;
    case 2: in = Wsp1; out = Wsp1Tc; R = 1024; C = 1024; obf = 1; break;
    case 3: in = Wsp1 + 1048576; out = Wsp1Tc + 1048576; R = 1024; C = 1024; obf = 1; break;
    case 4: in = W1c;  out = W1cT;   R = 1024; C = 512;  obf = 0; break;
    default: in = Wsp2; out = Wsp2T; R = 1024; C = 1024; obf = 0; break;
  }
  if (c0 >= C || r0 >= R) return;
  __shared__ float tile[32][33];
  for (int i = threadIdx.y; i < 32; i += 8)
    tile[i][threadIdx.x] = in[(size_t)(r0 + i) * C + c0 + threadIdx.x];
  __syncthreads();
  if (obf) {
    unsigned short* o = (unsigned short*)out;
    for (int i = threadIdx.y; i < 32; i += 8)
      o[(size_t)(c0 + i) * R + r0 + threadIdx.x] = f2b(tile[threadIdx.x][i]);
  } else {
    float* o = (float*)out;
    for (int i = threadIdx.y; i < 32; i += 8)
      o[(size_t)(c0 + i) * R + r0 + threadIdx.x] = tile[threadIdx.x][i];
  }
}

// ---------- small GEMM body, 8 A-rows per block ----------
__device__ __forceinline__ void rgemm8_body(int N, int M,
    const float* __restrict__ A, int lda, const float* __restrict__ B, int ldb,
    const float* __restrict__ bias, float* __restrict__ out, int ldc,
    int bx, int by, float* shf) {
  float (*Asm)[1024] = (float(*)[1024])shf;
  float (*red)[16][8] = (float(*)[16][8])(shf + 8192);
  int m0 = by * 8;
  for (int idx = threadIdx.x; idx < 8 * 1024; idx += 256) {
    int mm = idx >> 10, kk = idx & 1023;
    Asm[mm][kk] = (m0 + mm < M) ? A[(size_t)(m0 + mm) * lda + kk] : 0.f;
  }
  __syncthreads();
  int tx = threadIdx.x & 15, ty = threadIdx.x >> 4;
  int n = bx * 16 + tx;
  float acc[8] = {0.f, 0.f, 0.f, 0.f, 0.f, 0.f, 0.f, 0.f};
  if (n < N) {
    for (int k = ty * 64; k < ty * 64 + 64; ++k) {
      float bv = B[(size_t)k * ldb + n];
#pragma unroll
      for (int mm = 0; mm < 8; ++mm) acc[mm] = fmaf(Asm[mm][k], bv, acc[mm]);
    }
  }
#pragma unroll
  for (int mm = 0; mm < 8; ++mm) red[ty][tx][mm] = acc[mm];
  __syncthreads();
  if (ty < 8 && n < N && m0 + ty < M) {
    float s = 0.f;
#pragma unroll
    for (int q = 0; q < 16; ++q) s += red[q][tx][ty];
    if (bias) s += bias[n];
    out[(size_t)(m0 + ty) * ldc + n] = s;
  }
}

// lab = L@Wl+bl (z=0) and MmTf = L@Wsp2T (z=1)
__global__ __launch_bounds__(256) void rgemm8z_k(
    const float* __restrict__ L, const float* __restrict__ Wl,
    const float* __restrict__ bl, float* __restrict__ lab,
    const float* __restrict__ Wsp2T, float* __restrict__ MmTf) {
  __shared__ float shf[10240];
  if (blockIdx.z == 0) {
    rgemm8_body(2048, 32, L, 1024, Wl, 2048, bl, lab, 2048, blockIdx.x, blockIdx.y, shf);
  } else {
    if (blockIdx.x >= 64) return;
    rgemm8_body(1024, 32, L, 1024, Wsp2T, 1024, nullptr, MmTf, 1024,
                blockIdx.x, blockIdx.y, shf);
  }
}

// ---------- mega1: kmat + BvecB + misc + bt0A(K-parallel) ----------
__global__ __launch_bounds__(256) void mega1_k(
    const float* __restrict__ lab, const float* __restrict__ W1cT,
    unsigned short* __restrict__ KT,
    const float* __restrict__ W1b, const float* __restrict__ b1,
    float* __restrict__ BvecB,
    const float* __restrict__ bsp2, const float* __restrict__ L,
    float* __restrict__ cv, const float* __restrict__ MmTf,
    unsigned short* __restrict__ MmTb, const float* __restrict__ W2,
    unsigned short* __restrict__ W2padT, const float* __restrict__ bsp1,
    unsigned short* __restrict__ bsp1b,
    const float* __restrict__ bt, const float* __restrict__ W1a,
    float* __restrict__ bt0A) {
  __shared__ float shf[10240];
  int g = blockIdx.x;
  if (g < 8192) {  // KT[(c*512+d)][h] = l1[c][h] * W1c[h][d], 8 h/thread
    size_t gid = (size_t)g * 256 + threadIdx.x;
    int row = (int)(gid >> 7);
    int h0 = ((int)gid & 127) * 8;
    int c = row >> 9, d = row & 511;
    const float* lp = lab + (size_t)c * 2048 + 1024 + h0;
    const float* wp = W1cT + (size_t)d * 1024 + h0;
    float4 l0 = *(const float4*)lp, l1 = *(const float4*)(lp + 4);
    float4 w0 = *(const float4*)wp, w1 = *(const float4*)(wp + 4);
    bf16x8 o;
    o[0] = (short)f2b(l0.x * w0.x); o[1] = (short)f2b(l0.y * w0.y);
    o[2] = (short)f2b(l0.z * w0.z); o[3] = (short)f2b(l0.w * w0.w);
    o[4] = (short)f2b(l1.x * w1.x); o[5] = (short)f2b(l1.y * w1.y);
    o[6] = (short)f2b(l1.z * w1.z); o[7] = (short)f2b(l1.w * w1.w);
    *(bf16x8*)(KT + (size_t)row * 1024 + h0) = o;
  } else if (g < 8320) {  // BvecB = l0 @ W1b + b1   (32 x 512)
    int b = g - 8192;
    rgemm8_body(512, 32, lab, 2048, W1b, 512, b1, BvecB, 512, b & 31, b >> 5, shf);
  } else {
    int b = g - 8320;
    if (b < 32) {  // cv[c] = dot(bsp2, L[c])
      int c = b;
      float a = 0.f;
      for (int k = threadIdx.x; k < 1024; k += 256)
        a = fmaf(bsp2[k], L[(size_t)c * 1024 + k], a);
#pragma unroll
      for (int off = 32; off; off >>= 1) a += __shfl_down(a, off);
      if ((threadIdx.x & 63) == 0) shf[threadIdx.x >> 6] = a;
      __syncthreads();
      if (threadIdx.x == 0) cv[c] = shf[0] + shf[1] + shf[2] + shf[3];
    } else if (b < 64) {  // MmTf -> MmTb bf16
      int i = (b - 32) * 1024 + threadIdx.x * 4;
      float4 v = *(const float4*)(MmTf + i);
      *(ushort4*)(MmTb + i) = make_ushort4(f2b(v.x), f2b(v.y), f2b(v.z), f2b(v.w));
    } else if (b < 96) {  // W2padT[n][d] = n<3 ? W2[d][n] : 0
      int i = (b - 64) * 256 + threadIdx.x;
      int n = i >> 9, d = i & 511;
      W2padT[i] = f2b(n < 3 ? W2[d * 3 + n] : 0.f);
    } else if (b == 96) {  // bsp1 -> bsp1b bf16
      int i = threadIdx.x * 4;
      float4 v = *(const float4*)(bsp1 + i);
      *(ushort4*)(bsp1b + i) = make_ushort4(f2b(v.x), f2b(v.y), f2b(v.z), f2b(v.w));
    } else {  // b in [97,129): bt0A[d] = dot(bt[0:1024], W1a[:,d]), K-parallel
      float (*red)[16] = (float(*)[16])shf;
      int tx = threadIdx.x & 15, ty = threadIdx.x >> 4;
      int d = (b - 97) * 16 + tx;
      float a = 0.f;
      for (int k = ty * 64; k < ty * 64 + 64; ++k)
        a = fmaf(bt[k], W1a[(size_t)k * 512 + d], a);
      red[ty][tx] = a;
      __syncthreads();
      if (ty == 0) {
        float s = 0.f;
#pragma unroll
        for (int q = 0; q < 16; ++q) s += red[q][tx];
        bt0A[d] = s;
      }
    }
  }
}

// ---------- bf16 MFMA GEMM, 128x128 tile, BK=64, counted-vmcnt dbuf ----------
// MODE 1: merged N=4608: c<2048 tok(+bias)->out0/out1; <4096 -> out2 bf16 (UVb);
//         else Avec f32 = v + bias2[c-4096] -> outF (ld 512)
// MODE 3: out0 bf16 full tile (ld N)
template <int MODE>
__global__ __launch_bounds__(256) void gemm_k(
    const unsigned short* __restrict__ A, const unsigned short* __restrict__ BT,
    int N, int K,
    float* __restrict__ outF,
    unsigned short* __restrict__ out0, unsigned short* __restrict__ out1,
    unsigned short* __restrict__ out2,
    const float* __restrict__ bias, const float* __restrict__ bias2) {
  __shared__ __align__(16) unsigned short smem[2][16384];  // 64 KB dbuf
  int tid = threadIdx.x;
  int lane = tid & 63, wid = tid >> 6;
  int wr = wid >> 1, wc = wid & 1;
  int row0 = blockIdx.y * 128, col0 = blockIdx.x * 128;

  f32x4 zero4 = {0.f, 0.f, 0.f, 0.f};
  f32x4 acc[4][4];
#pragma unroll
  for (int i = 0; i < 4; ++i)
#pragma unroll
    for (int j = 0; j < 4; ++j) acc[i][j] = zero4;

  int srow = tid >> 3;
  int scol = ((tid & 7) ^ (srow & 7)) * 8;  // pre-swizzled global source
  const unsigned short* gA = A + (size_t)(row0 + srow) * K + scol;
  const unsigned short* gB = BT + (size_t)(col0 + srow) * K + scol;

  int fr = lane & 15, hi = lane >> 4;

#define G_STAGE(buf, kt)                                                     \
  {                                                                          \
    unsigned short* dA = smem[buf] + tid * 8;                                \
    unsigned short* dB = smem[buf] + 8192 + tid * 8;                         \
    _Pragma("unroll")                                                        \
    for (int i2 = 0; i2 < 4; ++i2) {                                         \
      GLOAD_LDS16(gA + (size_t)(i2 * 32) * K + (kt), dA + i2 * 2048);        \
      GLOAD_LDS16(gB + (size_t)(i2 * 32) * K + (kt), dB + i2 * 2048);        \
    }                                                                        \
  }

  G_STAGE(0, 0);

  int nt = K >> 6;
  for (int t = 0; t < nt; ++t) {
    if (t + 1 < nt) {
      G_STAGE((t + 1) & 1, (t + 1) << 6);
      asm volatile("s_waitcnt vmcnt(8)" ::: "memory");
    } else {
      asm volatile("s_waitcnt vmcnt(0)" ::: "memory");
    }
    __builtin_amdgcn_sched_barrier(0);
    __builtin_amdgcn_s_barrier();
    __builtin_amdgcn_sched_barrier(0);

    const unsigned short* As = smem[t & 1];
    const unsigned short* Bs = smem[t & 1] + 8192;
    bf16x8 af[4][2], bfr[4][2];
#pragma unroll
    for (int mi = 0; mi < 4; ++mi) {
      int rl = wr * 64 + mi * 16 + fr;
#pragma unroll
      for (int kk = 0; kk < 2; ++kk)
        af[mi][kk] = *(const bf16x8*)&As[rl * 64 + (((kk << 2) | hi) ^ (rl & 7)) * 8];
    }
#pragma unroll
    for (int ni = 0; ni < 4; ++ni) {
      int rl = wc * 64 + ni * 16 + fr;
#pragma unroll
      for (int kk = 0; kk < 2; ++kk)
        bfr[ni][kk] = *(const bf16x8*)&Bs[rl * 64 + (((kk << 2) | hi) ^ (rl & 7)) * 8];
    }
#pragma unroll
    for (int kk = 0; kk < 2; ++kk)
#pragma unroll
      for (int mi = 0; mi < 4; ++mi)
#pragma unroll
        for (int ni = 0; ni < 4; ++ni)
          acc[mi][ni] = __builtin_amdgcn_mfma_f32_16x16x32_bf16(af[mi][kk], bfr[ni][kk],
                                                                acc[mi][ni], 0, 0, 0);
    __builtin_amdgcn_sched_barrier(0);
    __builtin_amdgcn_s_barrier();
  }
#undef G_STAGE

  int rbase = row0 + wr * 64 + (hi << 2);
  int cbase = col0 + wc * 64 + fr;
#pragma unroll
  for (int mi = 0; mi < 4; ++mi) {
#pragma unroll
    for (int ni = 0; ni < 4; ++ni) {
      int ccol = cbase + ni * 16;
#pragma unroll
      for (int j = 0; j < 4; ++j) {
        int r = rbase + mi * 16 + j;
        float v = acc[mi][ni][j];
        if (MODE == 3) {
          out0[(size_t)r * N + ccol] = f2b(v);
        } else {
          if (ccol < 2048) {
            v += bias[ccol];
            if (ccol < 1024) out0[(size_t)r * 1024 + ccol] = f2b(v);
            else             out1[(size_t)r * 1024 + (ccol - 1024)] = f2b(v);
          } else if (ccol < 4096) {
            out2[(size_t)r * 2048 + (ccol - 2048)] = f2b(v);
          } else {
            outF[(size_t)r * 512 + (ccol - 4096)] = v + bias2[ccol - 4096];
          }
        }
      }
    }
  }
}

// ---------- E-GEMM: 256x256 tile, BK=64, 8-phase counted-vmcnt (T2+T3+T4+T5) ----------
// 8 waves (2m x 4n), 128 KB LDS dbuf. Region-free/stage schedule derived so that
// every stage targets a region freed >=1 barrier earlier, and vmcnt(6) at phases
// 4/8 lands the full next buffer before its first read (enumerated; tail vmcnt(0)).
__global__ __launch_bounds__(512, 2) void egemm8_k(
    const unsigned short* __restrict__ A,   // t1b [2048][1024]
    const unsigned short* __restrict__ BT,  // KmatT [16384][1024]
    const float* __restrict__ avec, const float* __restrict__ bvec,
    const unsigned short* __restrict__ w2t, float* __restrict__ sPart) {
  __shared__ __align__(16) unsigned short smem[2][32768];  // 2 x (A 32KB | B 32KB)
  int tid = threadIdx.x;
  int lane = tid & 63, wid = tid >> 6;
  int wm = wid >> 2, wn = wid & 3;
  int fr = lane & 15, hi = lane >> 4;
  // XCD swizzle: 512 = 8 xcd x 8 cb x 8 rb (rb fastest)
  int bid = blockIdx.x;
  int xcd = bid & 7, ii = bid >> 3;
  int cb = xcd * 8 + (ii >> 3);
  int rb = ii & 7;
  int row0 = rb * 256, col0 = cb * 256;
  int cc = col0 >> 9, dg0 = col0 & 511;

  f32x4 zero4 = {0.f, 0.f, 0.f, 0.f};
  f32x4 acc[8][4];
#pragma unroll
  for (int i = 0; i < 8; ++i)
#pragma unroll
    for (int j = 0; j < 4; ++j) acc[i][j] = zero4;

  // one block-wide issue: 64 rows = chunks [c0,c0+32) u [c1,c1+32); linear LDS,
  // pre-swizzled global source (slot ^ (row&7)); ktEl in elements.
#define EST(ldsbase, src, gbase, ktEl, c0, c1)                               \
  {                                                                          \
    int ar = (((tid < 256) ? (c0) : (c1)) + ((tid >> 3) & 31));              \
    const unsigned short* g = (src) + (size_t)((gbase) + ar) * 1024 +        \
                              (ktEl) + (((tid & 7) ^ (ar & 7)) * 8);         \
    unsigned short* d = (ldsbase) +                                          \
        ((((wid < 4) ? (c0) : (c1)) + ((wid & 3) * 8)) * 64) + lane * 8;     \
    GLOAD_LDS16(g, d);                                                       \
  }
#define ST_AMH0(b, kt) { EST(smem[b], A, row0, kt, 0, 32)  EST(smem[b], A, row0, kt, 128, 160) }
#define ST_AMH1(b, kt) { EST(smem[b], A, row0, kt, 64, 96) EST(smem[b], A, row0, kt, 192, 224) }
#define ST_BNH0(b, kt) { EST(smem[b] + 16384, BT, col0, kt, 0, 64)  EST(smem[b] + 16384, BT, col0, kt, 128, 192) }
#define ST_BNH1(b, kt) { EST(smem[b] + 16384, BT, col0, kt, 32, 96) EST(smem[b] + 16384, BT, col0, kt, 160, 224) }

  bf16x8 af[4][2], bfr[2][2][2];

#define LDA8(b, mh)                                                          \
  { _Pragma("unroll") for (int mi2 = 0; mi2 < 4; ++mi2) {                    \
      int rl = wm * 128 + (mh) * 64 + mi2 * 16 + fr;                         \
      _Pragma("unroll") for (int kk = 0; kk < 2; ++kk)                       \
        af[mi2][kk] = *(const bf16x8*)&smem[b][rl * 64 +                     \
            ((((kk << 2) | hi) ^ (rl & 7)) * 8)]; } }
#define LDB4(b, nh)                                                          \
  { _Pragma("unroll") for (int ni2 = 0; ni2 < 2; ++ni2) {                    \
      int rl = wn * 64 + (nh) * 32 + ni2 * 16 + fr;                          \
      _Pragma("unroll") for (int kk = 0; kk < 2; ++kk)                       \
        bfr[nh][ni2][kk] = *(const bf16x8*)&smem[b][16384 + rl * 64 +        \
            ((((kk << 2) | hi) ^ (rl & 7)) * 8)]; } }
#define MF16(mh, nh)                                                         \
  { _Pragma("unroll") for (int kk = 0; kk < 2; ++kk)                         \
    _Pragma("unroll") for (int mi2 = 0; mi2 < 4; ++mi2)                      \
    _Pragma("unroll") for (int ni2 = 0; ni2 < 2; ++ni2)                      \
      acc[(mh) * 4 + mi2][(nh) * 2 + ni2] =                                  \
          __builtin_amdgcn_mfma_f32_16x16x32_bf16(af[mi2][kk],               \
              bfr[nh][ni2][kk], acc[(mh) * 4 + mi2][(nh) * 2 + ni2], 0, 0, 0); }
#define BAR1                                                                 \
  __builtin_amdgcn_sched_barrier(0); __builtin_amdgcn_s_barrier();           \
  asm volatile("s_waitcnt lgkmcnt(0)" ::: "memory");                         \
  __builtin_amdgcn_sched_barrier(0); __builtin_amdgcn_s_setprio(1);
#define BAR2                                                                 \
  __builtin_amdgcn_s_setprio(0); __builtin_amdgcn_sched_barrier(0);          \
  __builtin_amdgcn_s_barrier();

  // prologue: tile0 fully + tile1 {AMH0,BNH0,BNH1}; vmcnt(6) lands all of tile0
  ST_AMH0(0, 0) ST_BNH0(0, 0) ST_BNH1(0, 0) ST_AMH1(0, 0)
  ST_AMH0(1, 64) ST_BNH0(1, 64) ST_BNH1(1, 64)
  asm volatile("s_waitcnt vmcnt(6)" ::: "memory");
  __builtin_amdgcn_sched_barrier(0);
  __builtin_amdgcn_s_barrier();

#pragma unroll 1
  for (int i = 0; i < 8; ++i) {
    int kt1 = i * 128 + 64;   // tile 2i+1
    int ktA = i * 128 + 128;  // tile 2i+2
    int ktB = i * 128 + 192;  // tile 2i+3
    bool pre = (i < 7);
    // ph1: read buf0 A-mh0 + B-nh0; stage A-mh1(2i+1 -> buf1)
    LDA8(0, 0) LDB4(0, 0)
    ST_AMH1(1, kt1)
    BAR1 MF16(0, 0) BAR2
    // ph2: read buf0 B-nh1; stage A-mh0(2i+2 -> buf0) [freed at ph1]
    LDB4(0, 1)
    if (pre) { ST_AMH0(0, ktA) }
    BAR1 MF16(0, 1) BAR2
    // ph3: read buf0 A-mh1; stage B-nh0(2i+2) [freed at ph1]
    LDA8(0, 1)
    if (pre) { ST_BNH0(0, ktA) }
    BAR1 MF16(1, 1) BAR2
    // ph4: stage B-nh1(2i+2) [freed at ph2]; vmcnt lands buf1 tile 2i+1
    if (pre) { ST_BNH1(0, ktA) }
    BAR1 MF16(1, 0)
    __builtin_amdgcn_s_setprio(0);
    if (pre) { asm volatile("s_waitcnt vmcnt(6)" ::: "memory"); }
    else     { asm volatile("s_waitcnt vmcnt(0)" ::: "memory"); }
    __builtin_amdgcn_sched_barrier(0);
    __builtin_amdgcn_s_barrier();
    // ph5: read buf1 A-mh0 + B-nh0; stage A-mh1(2i+2 -> buf0) [freed at ph3]
    LDA8(1, 0) LDB4(1, 0)
    if (pre) { ST_AMH1(0, ktA) }
    BAR1 MF16(0, 0) BAR2
    // ph6: read buf1 B-nh1; stage A-mh0(2i+3 -> buf1) [freed at ph5]
    LDB4(1, 1)
    if (pre) { ST_AMH0(1, ktB) }
    BAR1 MF16(0, 1) BAR2
    // ph7: read buf1 A-mh1; stage B-nh0(2i+3) [freed at ph5]
    LDA8(1, 1)
    if (pre) { ST_BNH0(1, ktB) }
    BAR1 MF16(1, 1) BAR2
    // ph8: stage B-nh1(2i+3) [freed at ph6]; vmcnt lands buf0 tile 2i+2
    if (pre) { ST_BNH1(1, ktB) }
    BAR1 MF16(1, 0)
    __builtin_amdgcn_s_setprio(0);
    if (pre) { asm volatile("s_waitcnt vmcnt(6)" ::: "memory"); }
    else     { asm volatile("s_waitcnt vmcnt(0)" ::: "memory"); }
    __builtin_amdgcn_sched_barrier(0);
    __builtin_amdgcn_s_barrier();
  }
#undef EST
#undef ST_AMH0
#undef ST_AMH1
#undef ST_BNH0
#undef ST_BNH1
#undef LDA8
#undef LDB4
#undef MF16
#undef BAR1
#undef BAR2

  // ---- epilogue: h = relu(acc+avec+bvec) -> swizzled LDS (128KB) -> W2 MFMA ----
  unsigned short* hsm = &smem[0][0];  // 256 rows x 256 ushort
#pragma unroll
  for (int mi = 0; mi < 8; ++mi) {
#pragma unroll
    for (int j = 0; j < 4; ++j) {
      int rl = wm * 128 + mi * 16 + hi * 4 + j;
      const float* avp = avec + (size_t)(row0 + rl) * 512 + dg0;
      const float* bvp = bvec + (size_t)cc * 512 + dg0;
#pragma unroll
      for (int ni = 0; ni < 4; ++ni) {
        int cl = wn * 64 + ni * 16 + fr;
        float v = acc[mi][ni][j] + avp[cl] + bvp[cl];
        v = fmaxf(v, 0.f);
        int sl = cl >> 3;
        hsm[rl * 256 + ((((sl ^ rl) & 7) | (sl & 24)) << 3) + (cl & 7)] = f2b(v);
      }
    }
  }
  __syncthreads();
  f32x4 s0 = zero4, s1 = zero4;
  int r0l = wid * 32 + fr;
  int r1l = wid * 32 + 16 + fr;
#pragma unroll
  for (int ks = 0; ks < 8; ++ks) {
    int sl = ks * 4 + hi;
    bf16x8 a0 = *(const bf16x8*)&hsm[r0l * 256 + ((((sl ^ r0l) & 7) | (sl & 24)) << 3)];
    bf16x8 a1 = *(const bf16x8*)&hsm[r1l * 256 + ((((sl ^ r1l) & 7) | (sl & 24)) << 3)];
    bf16x8 b = *(const bf16x8*)&w2t[(size_t)fr * 512 + dg0 + ks * 32 + hi * 8];
    s0 = __builtin_amdgcn_mfma_f32_16x16x32_bf16(a0, b, s0, 0, 0, 0);
    s1 = __builtin_amdgcn_mfma_f32_16x16x32_bf16(a1, b, s1, 0, 0, 0);
  }
  if (fr < 3) {
    float* sp = sPart + ((size_t)(cb & 1) * 2048 + row0 + wid * 32) * 96 + cc * 3 + fr;
#pragma unroll
    for (int j = 0; j < 4; ++j) {
      sp[(size_t)(hi * 4 + j) * 96] = s0[j];
      sp[(size_t)(16 + hi * 4 + j) * 96] = s1[j];
    }
  }
}

// ---------- fold 2 score slices + b2, then is_start/is_end ----------
__global__ __launch_bounds__(256) void foldmask_k(const float* __restrict__ part,
    const float* __restrict__ b2, float* __restrict__ outS,
    int* __restrict__ is_s, int* __restrict__ is_e) {
  __shared__ float sc[192];
  int b = blockIdx.x;
  int i = threadIdx.x;
  if (i < 192) {
    int idx = b * 192 + i;
    float s = b2[i % 3] + part[idx] + part[196608 + idx];
    outS[idx] = s;
    sc[i] = s;
  }
  __syncthreads();
  if (i < 2) {
    int s = 0, e = 0;
#pragma unroll
    for (int c = 0; c < 32; ++c) {
      s |= (sc[i * 96 + c * 3 + 0] >= 0.f);
      e |= (sc[i * 96 + c * 3 + 1] >= 0.f);
    }
    is_s[2 * b + i] = s;
    is_e[2 * b + i] = e;
  }
}

// ---------- fused span: 16 spans/wave, barrier-free, bf16 UV ----------
__global__ __launch_bounds__(256) void spanfuse_k(
    const unsigned short* __restrict__ UVb, const unsigned short* __restrict__ bsp1b,
    const unsigned short* __restrict__ MmTb, const float* __restrict__ cvv,
    const int* __restrict__ is_s, const int* __restrict__ is_e,
    float* __restrict__ outIdx, float* __restrict__ outMask,
    float* __restrict__ outLog) {
  __shared__ __align__(16) unsigned short Rs[4][16][32];
  int tid = threadIdx.x, lane = tid & 63, w = tid >> 6;
  int fr = lane & 15, hi = lane >> 4;
  int row = lane >> 2, q = lane & 3;
  int n = blockIdx.x * 64 + w * 16 + row;
  int wi = n / MAXW;
  int j = n - wi * MAXW;
  int er = wi + j;
  int valid = er < W_WORDS;
  int e = valid ? er : (W_WORDS - 1);
  int mask = (valid && is_s[wi] && is_e[e]) ? 1 : 0;
  if (q == 0) {
    outIdx[2 * n] = (float)wi;
    outIdx[2 * n + 1] = (float)e;
    outMask[n] = (float)mask;
  }
  int si = mask ? wi : 0, ei = mask ? e : 0;
  const unsigned short* Up = UVb + (size_t)si * 2048 + q * 8;
  const unsigned short* Vp = UVb + (size_t)ei * 2048 + 1024 + q * 8;
  const unsigned short* bp = bsp1b + q * 8;
  unsigned short* wRs = &Rs[w][0][0];
  f32x4 zero4 = {0.f, 0.f, 0.f, 0.f};
  f32x4 a0 = zero4, a1 = zero4;

  bf16x8 u = *(const bf16x8*)Up;
  bf16x8 v = *(const bf16x8*)Vp;
  bf16x8 bb = *(const bf16x8*)bp;
  bf16x8 fb0 = *(const bf16x8*)&MmTb[(size_t)fr * 1024 + hi * 8];
  bf16x8 fb1 = *(const bf16x8*)&MmTb[(size_t)(16 + fr) * 1024 + hi * 8];

  for (int kt = 0; kt < 32; ++kt) {
    int kn = ((kt + 1) & 31) * 32;
    bf16x8 un = *(const bf16x8*)(Up + kn);
    bf16x8 vn = *(const bf16x8*)(Vp + kn);
    bf16x8 bn = *(const bf16x8*)(bp + kn);
    bf16x8 f0n = *(const bf16x8*)&MmTb[(size_t)fr * 1024 + kn + hi * 8];
    bf16x8 f1n = *(const bf16x8*)&MmTb[(size_t)(16 + fr) * 1024 + kn + hi * 8];

    bf16x8 o;
#pragma unroll
    for (int i = 0; i < 8; ++i) {
      float s = b2f((unsigned short)u[i]) + b2f((unsigned short)v[i]) +
                b2f((unsigned short)bb[i]);
      o[i] = (short)f2b(fmaxf(s, 0.f));
    }
    *(bf16x8*)&wRs[row * 32 + (q ^ (row & 3)) * 8] = o;
    asm volatile("s_waitcnt lgkmcnt(0)" ::: "memory");
    bf16x8 fa = *(const bf16x8*)&wRs[fr * 32 + ((hi ^ (fr & 3)) & 3) * 8];
    a0 = __builtin_amdgcn_mfma_f32_16x16x32_bf16(fa, fb0, a0, 0, 0, 0);
    a1 = __builtin_amdgcn_mfma_f32_16x16x32_bf16(fa, fb1, a1, 0, 0, 0);
    u = un; v = vn; bb = bn; fb0 = f0n; fb1 = f1n;
  }

  int n0 = blockIdx.x * 64 + w * 16;
  float c0 = cvv[fr], c1 = cvv[16 + fr];
#pragma unroll
  for (int jj = 0; jj < 4; ++jj) {
    int nn = n0 + hi * 4 + jj;
    outLog[(size_t)nn * 32 + fr] = a0[jj] + c0;
    outLog[(size_t)nn * 32 + 16 + fr] = a1[jj] + c1;
  }
}

extern "C" void kernel_launch(void* const* d_in, const int* in_sizes, int n_in,
                              void* d_out, int out_size, void* d_ws, size_t ws_size,
                              hipStream_t stream) {
  const float* hs   = (const float*)d_in[0];
  const int*   wm   = (const int*)d_in[1];
  const float* L    = (const float*)d_in[2];
  const float* Wt   = (const float*)d_in[3];
  const float* bt   = (const float*)d_in[4];
  const float* Wl   = (const float*)d_in[5];
  const float* bl   = (const float*)d_in[6];
  const float* W1a  = (const float*)d_in[7];
  const float* W1b  = (const float*)d_in[8];
  const float* W1c  = (const float*)d_in[9];
  const float* b1   = (const float*)d_in[10];
  const float* W2   = (const float*)d_in[11];
  const float* b2   = (const float*)d_in[12];
  const float* Wsp1 = (const float*)d_in[13];
  const float* bsp1 = (const float*)d_in[14];
  const float* Wsp2 = (const float*)d_in[15];
  const float* bsp2 = (const float*)d_in[16];

  char* p = (char*)d_ws;
  auto alloc = [&p](size_t bytes) {
    char* r = p;
    p += (bytes + 255) & ~(size_t)255;
    return r;
  };
  unsigned short* we_b   = (unsigned short*)alloc((size_t)2048 * 1024 * 2);
  // WtT, Wsp1Tc, WfuseT MUST be adjacent: merged BT (4608 x 1024)
  unsigned short* WtT    = (unsigned short*)alloc((size_t)2048 * 1024 * 2);
  unsigned short* Wsp1Tc = (unsigned short*)alloc((size_t)2048 * 1024 * 2);
  unsigned short* WfuseT = (unsigned short*)alloc((size_t)512 * 1024 * 2);
  unsigned short* t0b    = (unsigned short*)alloc((size_t)2048 * 1024 * 2);
  unsigned short* t1b    = (unsigned short*)alloc((size_t)2048 * 1024 * 2);
  float*          lab    = (float*)alloc((size_t)32 * 2048 * 4);
  unsigned short* W1aT   = (unsigned short*)alloc((size_t)512 * 1024 * 2);
  unsigned short* Wtb0   = (unsigned short*)alloc((size_t)1024 * 1024 * 2);
  float*          Avec   = (float*)alloc((size_t)2048 * 512 * 4);
  float*          BvecB  = (float*)alloc((size_t)32 * 512 * 4);
  float*          bt0A   = (float*)alloc(512 * 4);
  float*          W1cT   = (float*)alloc((size_t)512 * 1024 * 4);
  unsigned short* KmatT  = (unsigned short*)alloc((size_t)16384 * 1024 * 2);
  float*          sPart  = (float*)alloc((size_t)2 * 2048 * 96 * 4);
  int*            is_s   = (int*)alloc(2048 * 4);
  int*            is_e   = (int*)alloc(2048 * 4);
  unsigned short* UVb    = (unsigned short*)alloc((size_t)2048 * 2048 * 2);
  float*          Wsp2T  = (float*)alloc((size_t)1024 * 1024 * 4);
  float*          MmTf   = (float*)alloc((size_t)32 * 1024 * 4);
  unsigned short* MmTb   = (unsigned short*)alloc((size_t)32 * 1024 * 2);
  float*          cv     = (float*)alloc(32 * 4);
  unsigned short* W2padT = (unsigned short*)alloc((size_t)16 * 512 * 2);
  unsigned short* bsp1b  = (unsigned short*)alloc((size_t)1024 * 2);

  float* outS    = (float*)d_out;
  float* outIdx  = outS + (size_t)2048 * 32 * 3;
  float* outMask = outIdx + (size_t)NSPAN * 2;
  float* outLog  = outMask + NSPAN;

  // transposes + gather + Wtb0 in one launch
  mega0_k<<<dim3(96, 32, 8), dim3(32, 8), 0, stream>>>(
      hs, wm, we_b, Wt, W1a, Wsp1, W1c, Wsp2, WtT, W1aT, Wsp1Tc, W1cT, Wsp2T, Wtb0);

  // lab = L@Wl+bl and MmTf = L@Wsp2T
  rgemm8z_k<<<dim3(128, 4, 2), 256, 0, stream>>>(L, Wl, bl, lab, Wsp2T, MmTf);

  // kmat + BvecB + misc + bt0A in one launch
  mega1_k<<<8449, 256, 0, stream>>>(lab, W1cT, KmatT, W1b, b1, BvecB,
                                    bsp2, L, cv, MmTf, MmTb, W2, W2padT, bsp1, bsp1b,
                                    bt, W1a, bt0A);

  // WfuseT = W1aT @ Wtb0^T  (512 x 1024 bf16): Avec folding matrix
  gemm_k<3><<<dim3(8, 4), 256, 0, stream>>>(W1aT, Wtb0, 1024, 1024, nullptr, WfuseT,
                                            nullptr, nullptr, nullptr, nullptr);
  // merged: [tok | UV | Avec] = we @ [Wt | Wsp1 | Wfuse]  (N = 4608)
  gemm_k<1><<<dim3(36, 16), 256, 0, stream>>>(we_b, WtT, 4608, 1024, Avec, t0b, t1b,
                                              UVb, bt, bt0A);
  // E-GEMM: 256^2 8-phase pipeline + fused score partials
  egemm8_k<<<512, 512, 0, stream>>>(t1b, KmatT, Avec, BvecB, W2padT, sPart);

  // fold scores + masks
  foldmask_k<<<1024, 256, 0, stream>>>(sPart, b2, outS, is_s, is_e);

  // fused span: 16 spans/wave, barrier-free
  spanfuse_k<<<384, 256, 0, stream>>>(UVb, bsp1b, MmTb, cv, is_s, is_e,
                                      outIdx, outMask, outLog);
}

// Round 12
// 228.651 us; speedup vs baseline: 1.0225x; 1.0225x over previous
//
#include <hip/hip_runtime.h>
#include <hip/hip_bf16.h>

#define W_WORDS 2048
#define H_DIM   1024
#define C_LAB   32
#define HID_D   512
#define MAXW    12
#define NSPAN   (W_WORDS * MAXW)

typedef __attribute__((ext_vector_type(8))) short bf16x8;
typedef __attribute__((ext_vector_type(4))) float f32x4;

__device__ __forceinline__ unsigned short f2b(float x) {
  union { float f; unsigned int i; } v; v.f = x;
  unsigned int r = v.i + 0x7FFFu + ((v.i >> 16) & 1u);
  return (unsigned short)(r >> 16);
}
__device__ __forceinline__ float b2f(unsigned short b) {
  union { float f; unsigned int i; } v; v.i = ((unsigned int)b) << 16;
  return v.f;
}

#define GLOAD_LDS16(g, l)                                                    \
  __builtin_amdgcn_global_load_lds(                                          \
      (const __attribute__((address_space(1))) unsigned int*)(g),            \
      (__attribute__((address_space(3))) unsigned int*)(l), 16, 0, 0)

// ---------- mega0: 6 transposes (z<6) + gather (z==6) + Wtb0 cvt (z==7) ----------
__global__ void mega0_k(const float* __restrict__ hs, const int* __restrict__ wm,
    unsigned short* __restrict__ we_b,
    const float* __restrict__ Wt, const float* __restrict__ W1a,
    const float* __restrict__ Wsp1, const float* __restrict__ W1c,
    const float* __restrict__ Wsp2,
    unsigned short* __restrict__ WtT, unsigned short* __restrict__ W1aT,
    unsigned short* __restrict__ Wsp1Tc, float* __restrict__ W1cT,
    float* __restrict__ Wsp2T, unsigned short* __restrict__ Wtb0) {
  if (blockIdx.z == 6) {  // gather: we_b[m-1] = bf16(hs[t])
    int t = blockIdx.y * 96 + blockIdx.x;
    int m = wm[t];
    if (m <= 0) return;
    const float* src = hs + (size_t)t * H_DIM;
    unsigned short* dst = we_b + (size_t)(m - 1) * H_DIM;
    int i = (threadIdx.y * 32 + threadIdx.x) * 4;
    float4 v = *(const float4*)(src + i);
    *(ushort4*)(dst + i) = make_ushort4(f2b(v.x), f2b(v.y), f2b(v.z), f2b(v.w));
    return;
  }
  int c0 = blockIdx.x * 32, r0 = blockIdx.y * 32;
  if (blockIdx.z == 7) {  // Wtb0[h][g] = bf16(Wt[h][g]), g<1024
    if (c0 >= 1024) return;
    for (int i = threadIdx.y; i < 32; i += 8)
      Wtb0[(size_t)(r0 + i) * 1024 + c0 + threadIdx.x] =
          f2b(Wt[(size_t)(r0 + i) * 2048 + c0 + threadIdx.x]);
    return;
  }
  const float* in;
  void* out;
  int R, C, obf;
  switch (blockIdx.z) {
    case 0: in = Wt;   out = WtT;    R = 1024; C = 2048; obf = 1; break;
    case 1: in = W1a;  out = W1aT;   R = 1024; C = 512;  obf = 1; break;
    case 2: in = Wsp1; out = Wsp1Tc; R = 1024; C = 1024; obf = 1; break;
    case 3: in = Wsp1 + 1048576; out = Wsp1Tc + 1048576; R = 1024; C = 1024; obf = 1; break;
    case 4: in = W1c;  out = W1cT;   R = 1024; C = 512;  obf = 0; break;
    default: in = Wsp2; out = Wsp2T; R = 1024; C = 1024; obf = 0; break;
  }
  if (c0 >= C || r0 >= R) return;
  __shared__ float tile[32][33];
  for (int i = threadIdx.y; i < 32; i += 8)
    tile[i][threadIdx.x] = in[(size_t)(r0 + i) * C + c0 + threadIdx.x];
  __syncthreads();
  if (obf) {
    unsigned short* o = (unsigned short*)out;
    for (int i = threadIdx.y; i < 32; i += 8)
      o[(size_t)(c0 + i) * R + r0 + threadIdx.x] = f2b(tile[threadIdx.x][i]);
  } else {
    float* o = (float*)out;
    for (int i = threadIdx.y; i < 32; i += 8)
      o[(size_t)(c0 + i) * R + r0 + threadIdx.x] = tile[threadIdx.x][i];
  }
}

// ---------- small GEMM body, 8 A-rows per block ----------
__device__ __forceinline__ void rgemm8_body(int N, int M,
    const float* __restrict__ A, int lda, const float* __restrict__ B, int ldb,
    const float* __restrict__ bias, float* __restrict__ out, int ldc,
    int bx, int by, float* shf) {
  float (*Asm)[1024] = (float(*)[1024])shf;
  float (*red)[16][8] = (float(*)[16][8])(shf + 8192);
  int m0 = by * 8;
  for (int idx = threadIdx.x; idx < 8 * 1024; idx += 256) {
    int mm = idx >> 10, kk = idx & 1023;
    Asm[mm][kk] = (m0 + mm < M) ? A[(size_t)(m0 + mm) * lda + kk] : 0.f;
  }
  __syncthreads();
  int tx = threadIdx.x & 15, ty = threadIdx.x >> 4;
  int n = bx * 16 + tx;
  float acc[8] = {0.f, 0.f, 0.f, 0.f, 0.f, 0.f, 0.f, 0.f};
  if (n < N) {
    for (int k = ty * 64; k < ty * 64 + 64; ++k) {
      float bv = B[(size_t)k * ldb + n];
#pragma unroll
      for (int mm = 0; mm < 8; ++mm) acc[mm] = fmaf(Asm[mm][k], bv, acc[mm]);
    }
  }
#pragma unroll
  for (int mm = 0; mm < 8; ++mm) red[ty][tx][mm] = acc[mm];
  __syncthreads();
  if (ty < 8 && n < N && m0 + ty < M) {
    float s = 0.f;
#pragma unroll
    for (int q = 0; q < 16; ++q) s += red[q][tx][ty];
    if (bias) s += bias[n];
    out[(size_t)(m0 + ty) * ldc + n] = s;
  }
}

// lab = L@Wl+bl (z=0) and MmTf = L@Wsp2T (z=1)
__global__ __launch_bounds__(256) void rgemm8z_k(
    const float* __restrict__ L, const float* __restrict__ Wl,
    const float* __restrict__ bl, float* __restrict__ lab,
    const float* __restrict__ Wsp2T, float* __restrict__ MmTf) {
  __shared__ float shf[10240];
  if (blockIdx.z == 0) {
    rgemm8_body(2048, 32, L, 1024, Wl, 2048, bl, lab, 2048, blockIdx.x, blockIdx.y, shf);
  } else {
    if (blockIdx.x >= 64) return;
    rgemm8_body(1024, 32, L, 1024, Wsp2T, 1024, nullptr, MmTf, 1024,
                blockIdx.x, blockIdx.y, shf);
  }
}

// ---------- mega1: kmat + BvecB + misc + bt0A(K-parallel) ----------
__global__ __launch_bounds__(256) void mega1_k(
    const float* __restrict__ lab, const float* __restrict__ W1cT,
    unsigned short* __restrict__ KT,
    const float* __restrict__ W1b, const float* __restrict__ b1,
    float* __restrict__ BvecB,
    const float* __restrict__ bsp2, const float* __restrict__ L,
    float* __restrict__ cv, const float* __restrict__ MmTf,
    unsigned short* __restrict__ MmTb, const float* __restrict__ W2,
    unsigned short* __restrict__ W2padT, const float* __restrict__ bsp1,
    unsigned short* __restrict__ bsp1b,
    const float* __restrict__ bt, const float* __restrict__ W1a,
    float* __restrict__ bt0A) {
  __shared__ float shf[10240];
  int g = blockIdx.x;
  if (g < 8192) {  // KT[(c*512+d)][h] = l1[c][h] * W1c[h][d], 8 h/thread
    size_t gid = (size_t)g * 256 + threadIdx.x;
    int row = (int)(gid >> 7);
    int h0 = ((int)gid & 127) * 8;
    int c = row >> 9, d = row & 511;
    const float* lp = lab + (size_t)c * 2048 + 1024 + h0;
    const float* wp = W1cT + (size_t)d * 1024 + h0;
    float4 l0 = *(const float4*)lp, l1 = *(const float4*)(lp + 4);
    float4 w0 = *(const float4*)wp, w1 = *(const float4*)(wp + 4);
    bf16x8 o;
    o[0] = (short)f2b(l0.x * w0.x); o[1] = (short)f2b(l0.y * w0.y);
    o[2] = (short)f2b(l0.z * w0.z); o[3] = (short)f2b(l0.w * w0.w);
    o[4] = (short)f2b(l1.x * w1.x); o[5] = (short)f2b(l1.y * w1.y);
    o[6] = (short)f2b(l1.z * w1.z); o[7] = (short)f2b(l1.w * w1.w);
    *(bf16x8*)(KT + (size_t)row * 1024 + h0) = o;
  } else if (g < 8320) {  // BvecB = l0 @ W1b + b1   (32 x 512)
    int b = g - 8192;
    rgemm8_body(512, 32, lab, 2048, W1b, 512, b1, BvecB, 512, b & 31, b >> 5, shf);
  } else {
    int b = g - 8320;
    if (b < 32) {  // cv[c] = dot(bsp2, L[c])
      int c = b;
      float a = 0.f;
      for (int k = threadIdx.x; k < 1024; k += 256)
        a = fmaf(bsp2[k], L[(size_t)c * 1024 + k], a);
#pragma unroll
      for (int off = 32; off; off >>= 1) a += __shfl_down(a, off);
      if ((threadIdx.x & 63) == 0) shf[threadIdx.x >> 6] = a;
      __syncthreads();
      if (threadIdx.x == 0) cv[c] = shf[0] + shf[1] + shf[2] + shf[3];
    } else if (b < 64) {  // MmTf -> MmTb bf16
      int i = (b - 32) * 1024 + threadIdx.x * 4;
      float4 v = *(const float4*)(MmTf + i);
      *(ushort4*)(MmTb + i) = make_ushort4(f2b(v.x), f2b(v.y), f2b(v.z), f2b(v.w));
    } else if (b < 96) {  // W2padT[n][d] = n<3 ? W2[d][n] : 0
      int i = (b - 64) * 256 + threadIdx.x;
      int n = i >> 9, d = i & 511;
      W2padT[i] = f2b(n < 3 ? W2[d * 3 + n] : 0.f);
    } else if (b == 96) {  // bsp1 -> bsp1b bf16
      int i = threadIdx.x * 4;
      float4 v = *(const float4*)(bsp1 + i);
      *(ushort4*)(bsp1b + i) = make_ushort4(f2b(v.x), f2b(v.y), f2b(v.z), f2b(v.w));
    } else {  // b in [97,129): bt0A[d] = dot(bt[0:1024], W1a[:,d]), K-parallel
      float (*red)[16] = (float(*)[16])shf;
      int tx = threadIdx.x & 15, ty = threadIdx.x >> 4;
      int d = (b - 97) * 16 + tx;
      float a = 0.f;
      for (int k = ty * 64; k < ty * 64 + 64; ++k)
        a = fmaf(bt[k], W1a[(size_t)k * 512 + d], a);
      red[ty][tx] = a;
      __syncthreads();
      if (ty == 0) {
        float s = 0.f;
#pragma unroll
        for (int q = 0; q < 16; ++q) s += red[q][tx];
        bt0A[d] = s;
      }
    }
  }
}

// ---------- bf16 MFMA GEMM, 128x128 tile, BK=64, counted-vmcnt dbuf ----------
// MODE 1: merged N=4608: c<2048 tok(+bias)->out0/out1; <4096 -> out2 bf16 (UVb);
//         else Avec f32 = v + bias2[c-4096] -> outF (ld 512)
// MODE 3: out0 bf16 full tile (ld N)
template <int MODE>
__global__ __launch_bounds__(256) void gemm_k(
    const unsigned short* __restrict__ A, const unsigned short* __restrict__ BT,
    int N, int K,
    float* __restrict__ outF,
    unsigned short* __restrict__ out0, unsigned short* __restrict__ out1,
    unsigned short* __restrict__ out2,
    const float* __restrict__ bias, const float* __restrict__ bias2) {
  __shared__ __align__(16) unsigned short smem[2][16384];  // 64 KB dbuf
  int tid = threadIdx.x;
  int lane = tid & 63, wid = tid >> 6;
  int wr = wid >> 1, wc = wid & 1;
  int row0 = blockIdx.y * 128, col0 = blockIdx.x * 128;

  f32x4 zero4 = {0.f, 0.f, 0.f, 0.f};
  f32x4 acc[4][4];
#pragma unroll
  for (int i = 0; i < 4; ++i)
#pragma unroll
    for (int j = 0; j < 4; ++j) acc[i][j] = zero4;

  int srow = tid >> 3;
  int scol = ((tid & 7) ^ (srow & 7)) * 8;  // pre-swizzled global source
  const unsigned short* gA = A + (size_t)(row0 + srow) * K + scol;
  const unsigned short* gB = BT + (size_t)(col0 + srow) * K + scol;

  int fr = lane & 15, hi = lane >> 4;

#define G_STAGE(buf, kt)                                                     \
  {                                                                          \
    unsigned short* dA = smem[buf] + tid * 8;                                \
    unsigned short* dB = smem[buf] + 8192 + tid * 8;                         \
    _Pragma("unroll")                                                        \
    for (int i2 = 0; i2 < 4; ++i2) {                                         \
      GLOAD_LDS16(gA + (size_t)(i2 * 32) * K + (kt), dA + i2 * 2048);        \
      GLOAD_LDS16(gB + (size_t)(i2 * 32) * K + (kt), dB + i2 * 2048);        \
    }                                                                        \
  }

  G_STAGE(0, 0);

  int nt = K >> 6;
  for (int t = 0; t < nt; ++t) {
    if (t + 1 < nt) {
      G_STAGE((t + 1) & 1, (t + 1) << 6);
      asm volatile("s_waitcnt vmcnt(8)" ::: "memory");
    } else {
      asm volatile("s_waitcnt vmcnt(0)" ::: "memory");
    }
    __builtin_amdgcn_sched_barrier(0);
    __builtin_amdgcn_s_barrier();
    __builtin_amdgcn_sched_barrier(0);

    const unsigned short* As = smem[t & 1];
    const unsigned short* Bs = smem[t & 1] + 8192;
    bf16x8 af[4][2], bfr[4][2];
#pragma unroll
    for (int mi = 0; mi < 4; ++mi) {
      int rl = wr * 64 + mi * 16 + fr;
#pragma unroll
      for (int kk = 0; kk < 2; ++kk)
        af[mi][kk] = *(const bf16x8*)&As[rl * 64 + (((kk << 2) | hi) ^ (rl & 7)) * 8];
    }
#pragma unroll
    for (int ni = 0; ni < 4; ++ni) {
      int rl = wc * 64 + ni * 16 + fr;
#pragma unroll
      for (int kk = 0; kk < 2; ++kk)
        bfr[ni][kk] = *(const bf16x8*)&Bs[rl * 64 + (((kk << 2) | hi) ^ (rl & 7)) * 8];
    }
#pragma unroll
    for (int kk = 0; kk < 2; ++kk)
#pragma unroll
      for (int mi = 0; mi < 4; ++mi)
#pragma unroll
        for (int ni = 0; ni < 4; ++ni)
          acc[mi][ni] = __builtin_amdgcn_mfma_f32_16x16x32_bf16(af[mi][kk], bfr[ni][kk],
                                                                acc[mi][ni], 0, 0, 0);
    __builtin_amdgcn_sched_barrier(0);
    __builtin_amdgcn_s_barrier();
  }
#undef G_STAGE

  int rbase = row0 + wr * 64 + (hi << 2);
  int cbase = col0 + wc * 64 + fr;
#pragma unroll
  for (int mi = 0; mi < 4; ++mi) {
#pragma unroll
    for (int ni = 0; ni < 4; ++ni) {
      int ccol = cbase + ni * 16;
#pragma unroll
      for (int j = 0; j < 4; ++j) {
        int r = rbase + mi * 16 + j;
        float v = acc[mi][ni][j];
        if (MODE == 3) {
          out0[(size_t)r * N + ccol] = f2b(v);
        } else {
          if (ccol < 2048) {
            v += bias[ccol];
            if (ccol < 1024) out0[(size_t)r * 1024 + ccol] = f2b(v);
            else             out1[(size_t)r * 1024 + (ccol - 1024)] = f2b(v);
          } else if (ccol < 4096) {
            out2[(size_t)r * 2048 + (ccol - 2048)] = f2b(v);
          } else {
            outF[(size_t)r * 512 + (ccol - 4096)] = v + bias2[ccol - 4096];
          }
        }
      }
    }
  }
}

// ---------- E-GEMM: 128² tile, BK=64, counted-vmcnt dbuf, 8x8 supertile ----------
// h = relu(gemm + avec + bvec) -> swizzled LDS -> MFMA vs W2padT -> sPart slice.
__global__ __launch_bounds__(256) void egemm_k(
    const unsigned short* __restrict__ A,   // t1b [2048][1024]
    const unsigned short* __restrict__ BT,  // KmatT [16384][1024]
    const float* __restrict__ avec, const float* __restrict__ bvec,
    const unsigned short* __restrict__ w2t, float* __restrict__ sPart) {
  __shared__ __align__(16) unsigned short smem[2][16384];  // 64 KB dbuf
  int tid = threadIdx.x;
  int lane = tid & 63, wid = tid >> 6;
  int wr = wid >> 1, wc = wid & 1;
  // 8 xcd x (2x2 supergrid of 8rb x 8cb supertiles): L2 set = 2MB A + 2MB B
  int bid = blockIdx.x;
  int xcd = bid & 7, ii = bid >> 3;
  int sg = ii >> 6, inner = ii & 63;
  int rb = ((sg >> 1) << 3) | (inner & 7);
  int cb = xcd * 16 + (((sg & 1) << 3) | (inner >> 3));
  int row0 = rb * 128, col0 = cb * 128, cbq = cb & 3;

  f32x4 zero4 = {0.f, 0.f, 0.f, 0.f};
  f32x4 acc[4][4];
#pragma unroll
  for (int i = 0; i < 4; ++i)
#pragma unroll
    for (int j = 0; j < 4; ++j) acc[i][j] = zero4;

  int srow = tid >> 3;
  int scol = ((tid & 7) ^ (srow & 7)) * 8;
  const unsigned short* gA = A + (size_t)(row0 + srow) * 1024 + scol;
  const unsigned short* gB = BT + (size_t)(col0 + srow) * 1024 + scol;

  int fr = lane & 15, hi = lane >> 4;

#define E_STAGE(buf, kt)                                                     \
  {                                                                          \
    unsigned short* dA = smem[buf] + tid * 8;                                \
    unsigned short* dB = smem[buf] + 8192 + tid * 8;                         \
    _Pragma("unroll")                                                        \
    for (int i2 = 0; i2 < 4; ++i2) {                                         \
      GLOAD_LDS16(gA + (size_t)(i2 * 32) * 1024 + (kt), dA + i2 * 2048);     \
      GLOAD_LDS16(gB + (size_t)(i2 * 32) * 1024 + (kt), dB + i2 * 2048);     \
    }                                                                        \
  }

  E_STAGE(0, 0);

  for (int t = 0; t < 16; ++t) {
    if (t + 1 < 16) {
      E_STAGE((t + 1) & 1, (t + 1) << 6);
      asm volatile("s_waitcnt vmcnt(8)" ::: "memory");
    } else {
      asm volatile("s_waitcnt vmcnt(0)" ::: "memory");
    }
    __builtin_amdgcn_sched_barrier(0);
    __builtin_amdgcn_s_barrier();
    __builtin_amdgcn_sched_barrier(0);

    const unsigned short* As = smem[t & 1];
    const unsigned short* Bs = smem[t & 1] + 8192;
    bf16x8 af[4][2], bfr[4][2];
#pragma unroll
    for (int mi = 0; mi < 4; ++mi) {
      int rl = wr * 64 + mi * 16 + fr;
#pragma unroll
      for (int kk = 0; kk < 2; ++kk)
        af[mi][kk] = *(const bf16x8*)&As[rl * 64 + (((kk << 2) | hi) ^ (rl & 7)) * 8];
    }
#pragma unroll
    for (int ni = 0; ni < 4; ++ni) {
      int rl = wc * 64 + ni * 16 + fr;
#pragma unroll
      for (int kk = 0; kk < 2; ++kk)
        bfr[ni][kk] = *(const bf16x8*)&Bs[rl * 64 + (((kk << 2) | hi) ^ (rl & 7)) * 8];
    }
#pragma unroll
    for (int kk = 0; kk < 2; ++kk)
#pragma unroll
      for (int mi = 0; mi < 4; ++mi)
#pragma unroll
        for (int ni = 0; ni < 4; ++ni)
          acc[mi][ni] = __builtin_amdgcn_mfma_f32_16x16x32_bf16(af[mi][kk], bfr[ni][kk],
                                                                acc[mi][ni], 0, 0, 0);
    __builtin_amdgcn_sched_barrier(0);
    __builtin_amdgcn_s_barrier();
  }
#undef E_STAGE

  // ---- epilogue: h -> swizzled LDS (32 KB of smem[0]) -> W2 MFMA ----
  unsigned short* hsm = &smem[0][0];
  int cc = col0 >> 9;
  int dg0 = col0 & 511;
#pragma unroll
  for (int mi = 0; mi < 4; ++mi) {
#pragma unroll
    for (int j = 0; j < 4; ++j) {
      int rl = wr * 64 + hi * 4 + mi * 16 + j;
      const float* avp = avec + (size_t)(row0 + rl) * 512 + dg0;
      const float* bvp = bvec + (size_t)cc * 512 + dg0;
#pragma unroll
      for (int ni = 0; ni < 4; ++ni) {
        int cl = wc * 64 + ni * 16 + fr;
        float v = acc[mi][ni][j] + avp[cl] + bvp[cl];
        v = fmaxf(v, 0.f);
        int slot = cl >> 3;
        hsm[rl * 128 + (((slot ^ rl) & 7) << 3) + (slot & 8) * 8 + (cl & 7)] = f2b(v);
      }
    }
  }
  __syncthreads();
  f32x4 s0 = zero4, s1 = zero4;
  int r0l = wid * 32 + fr;
  int r1l = wid * 32 + 16 + fr;
#pragma unroll
  for (int kt2 = 0; kt2 < 4; ++kt2) {
    int slot = kt2 * 4 + hi;
    bf16x8 a0 = *(const bf16x8*)&hsm[r0l * 128 + (((slot ^ r0l) & 7) << 3) + (slot & 8) * 8];
    bf16x8 a1 = *(const bf16x8*)&hsm[r1l * 128 + (((slot ^ r1l) & 7) << 3) + (slot & 8) * 8];
    bf16x8 b = *(const bf16x8*)&w2t[(size_t)fr * 512 + dg0 + kt2 * 32 + hi * 8];
    s0 = __builtin_amdgcn_mfma_f32_16x16x32_bf16(a0, b, s0, 0, 0, 0);
    s1 = __builtin_amdgcn_mfma_f32_16x16x32_bf16(a1, b, s1, 0, 0, 0);
  }
  if (fr < 3) {
    float* sp = sPart + ((size_t)cbq * 2048 + row0) * 96 + cc * 3 + fr;
#pragma unroll
    for (int j = 0; j < 4; ++j) {
      sp[(size_t)(wid * 32 + hi * 4 + j) * 96] = s0[j];
      sp[(size_t)(wid * 32 + 16 + hi * 4 + j) * 96] = s1[j];
    }
  }
}

// ---------- fold 4 score slices + b2, then is_start/is_end ----------
__global__ __launch_bounds__(256) void foldmask_k(const float* __restrict__ part,
    const float* __restrict__ b2, float* __restrict__ outS,
    int* __restrict__ is_s, int* __restrict__ is_e) {
  __shared__ float sc[192];
  int b = blockIdx.x;
  int i = threadIdx.x;
  if (i < 192) {
    int idx = b * 192 + i;
    float s = b2[i % 3] + part[idx] + part[196608 + idx] +
              part[2 * 196608 + idx] + part[3 * 196608 + idx];
    outS[idx] = s;
    sc[i] = s;
  }
  __syncthreads();
  if (i < 2) {
    int s = 0, e = 0;
#pragma unroll
    for (int c = 0; c < 32; ++c) {
      s |= (sc[i * 96 + c * 3 + 0] >= 0.f);
      e |= (sc[i * 96 + c * 3 + 1] >= 0.f);
    }
    is_s[2 * b + i] = s;
    is_e[2 * b + i] = e;
  }
}

// ---------- fused span: 16 spans/wave, barrier-free, 2-step unrolled ----------
__global__ __launch_bounds__(256) void spanfuse_k(
    const unsigned short* __restrict__ UVb, const unsigned short* __restrict__ bsp1b,
    const unsigned short* __restrict__ MmTb, const float* __restrict__ cvv,
    const int* __restrict__ is_s, const int* __restrict__ is_e,
    float* __restrict__ outIdx, float* __restrict__ outMask,
    float* __restrict__ outLog) {
  __shared__ __align__(16) unsigned short Rs[4][2][16][32];  // 8 KB
  int tid = threadIdx.x, lane = tid & 63, w = tid >> 6;
  int fr = lane & 15, hi = lane >> 4;
  int row = lane >> 2, q = lane & 3;
  int n = blockIdx.x * 64 + w * 16 + row;
  int wi = n / MAXW;
  int j = n - wi * MAXW;
  int er = wi + j;
  int valid = er < W_WORDS;
  int e = valid ? er : (W_WORDS - 1);
  int mask = (valid && is_s[wi] && is_e[e]) ? 1 : 0;
  if (q == 0) {
    outIdx[2 * n] = (float)wi;
    outIdx[2 * n + 1] = (float)e;
    outMask[n] = (float)mask;
  }
  int si = mask ? wi : 0, ei = mask ? e : 0;
  const unsigned short* Up = UVb + (size_t)si * 2048 + q * 8;
  const unsigned short* Vp = UVb + (size_t)ei * 2048 + 1024 + q * 8;
  const unsigned short* bp = bsp1b + q * 8;
  const unsigned short* M0 = MmTb + (size_t)fr * 1024 + hi * 8;
  const unsigned short* M1 = MmTb + (size_t)(16 + fr) * 1024 + hi * 8;
  unsigned short* wRs0 = &Rs[w][0][0][0];
  unsigned short* wRs1 = &Rs[w][1][0][0];
  int wslot = (q ^ (row & 3)) * 8;
  int rslot = ((hi ^ (fr & 3)) & 3) * 8;
  f32x4 zero4 = {0.f, 0.f, 0.f, 0.f};
  f32x4 a0 = zero4, a1 = zero4;

  // current pair (kt, kt+1)
  bf16x8 u0 = *(const bf16x8*)Up,        v0 = *(const bf16x8*)Vp;
  bf16x8 b0 = *(const bf16x8*)bp;
  bf16x8 u1 = *(const bf16x8*)(Up + 32), v1 = *(const bf16x8*)(Vp + 32);
  bf16x8 b1v = *(const bf16x8*)(bp + 32);
  bf16x8 f00 = *(const bf16x8*)M0,        f10 = *(const bf16x8*)M1;
  bf16x8 f01 = *(const bf16x8*)(M0 + 32), f11 = *(const bf16x8*)(M1 + 32);

  for (int kt = 0; kt < 32; kt += 2) {
    int ka = ((kt + 2) & 31) * 32, kb = ((kt + 3) & 31) * 32;
    bf16x8 nu0 = *(const bf16x8*)(Up + ka), nv0 = *(const bf16x8*)(Vp + ka);
    bf16x8 nb0 = *(const bf16x8*)(bp + ka);
    bf16x8 nu1 = *(const bf16x8*)(Up + kb), nv1 = *(const bf16x8*)(Vp + kb);
    bf16x8 nb1 = *(const bf16x8*)(bp + kb);
    bf16x8 nf00 = *(const bf16x8*)(M0 + ka), nf10 = *(const bf16x8*)(M1 + ka);
    bf16x8 nf01 = *(const bf16x8*)(M0 + kb), nf11 = *(const bf16x8*)(M1 + kb);

    bf16x8 o0, o1;
#pragma unroll
    for (int i = 0; i < 8; ++i) {
      o0[i] = (short)f2b(fmaxf(b2f((unsigned short)u0[i]) + b2f((unsigned short)v0[i]) +
                               b2f((unsigned short)b0[i]), 0.f));
      o1[i] = (short)f2b(fmaxf(b2f((unsigned short)u1[i]) + b2f((unsigned short)v1[i]) +
                               b2f((unsigned short)b1v[i]), 0.f));
    }
    *(bf16x8*)&wRs0[row * 32 + wslot] = o0;
    *(bf16x8*)&wRs1[row * 32 + wslot] = o1;
    asm volatile("s_waitcnt lgkmcnt(0)" ::: "memory");
    bf16x8 fa0 = *(const bf16x8*)&wRs0[fr * 32 + rslot];
    bf16x8 fa1 = *(const bf16x8*)&wRs1[fr * 32 + rslot];
    a0 = __builtin_amdgcn_mfma_f32_16x16x32_bf16(fa0, f00, a0, 0, 0, 0);
    a1 = __builtin_amdgcn_mfma_f32_16x16x32_bf16(fa0, f10, a1, 0, 0, 0);
    a0 = __builtin_amdgcn_mfma_f32_16x16x32_bf16(fa1, f01, a0, 0, 0, 0);
    a1 = __builtin_amdgcn_mfma_f32_16x16x32_bf16(fa1, f11, a1, 0, 0, 0);
    u0 = nu0; v0 = nv0; b0 = nb0;
    u1 = nu1; v1 = nv1; b1v = nb1;
    f00 = nf00; f10 = nf10; f01 = nf01; f11 = nf11;
  }

  int n0 = blockIdx.x * 64 + w * 16;
  float c0 = cvv[fr], c1 = cvv[16 + fr];
#pragma unroll
  for (int jj = 0; jj < 4; ++jj) {
    int nn = n0 + hi * 4 + jj;
    outLog[(size_t)nn * 32 + fr] = a0[jj] + c0;
    outLog[(size_t)nn * 32 + 16 + fr] = a1[jj] + c1;
  }
}

extern "C" void kernel_launch(void* const* d_in, const int* in_sizes, int n_in,
                              void* d_out, int out_size, void* d_ws, size_t ws_size,
                              hipStream_t stream) {
  const float* hs   = (const float*)d_in[0];
  const int*   wm   = (const int*)d_in[1];
  const float* L    = (const float*)d_in[2];
  const float* Wt   = (const float*)d_in[3];
  const float* bt   = (const float*)d_in[4];
  const float* Wl   = (const float*)d_in[5];
  const float* bl   = (const float*)d_in[6];
  const float* W1a  = (const float*)d_in[7];
  const float* W1b  = (const float*)d_in[8];
  const float* W1c  = (const float*)d_in[9];
  const float* b1   = (const float*)d_in[10];
  const float* W2   = (const float*)d_in[11];
  const float* b2   = (const float*)d_in[12];
  const float* Wsp1 = (const float*)d_in[13];
  const float* bsp1 = (const float*)d_in[14];
  const float* Wsp2 = (const float*)d_in[15];
  const float* bsp2 = (const float*)d_in[16];

  char* p = (char*)d_ws;
  auto alloc = [&p](size_t bytes) {
    char* r = p;
    p += (bytes + 255) & ~(size_t)255;
    return r;
  };
  unsigned short* we_b   = (unsigned short*)alloc((size_t)2048 * 1024 * 2);
  // WtT, Wsp1Tc, WfuseT MUST be adjacent: merged BT (4608 x 1024)
  unsigned short* WtT    = (unsigned short*)alloc((size_t)2048 * 1024 * 2);
  unsigned short* Wsp1Tc = (unsigned short*)alloc((size_t)2048 * 1024 * 2);
  unsigned short* WfuseT = (unsigned short*)alloc((size_t)512 * 1024 * 2);
  unsigned short* t0b    = (unsigned short*)alloc((size_t)2048 * 1024 * 2);
  unsigned short* t1b    = (unsigned short*)alloc((size_t)2048 * 1024 * 2);
  float*          lab    = (float*)alloc((size_t)32 * 2048 * 4);
  unsigned short* W1aT   = (unsigned short*)alloc((size_t)512 * 1024 * 2);
  unsigned short* Wtb0   = (unsigned short*)alloc((size_t)1024 * 1024 * 2);
  float*          Avec   = (float*)alloc((size_t)2048 * 512 * 4);
  float*          BvecB  = (float*)alloc((size_t)32 * 512 * 4);
  float*          bt0A   = (float*)alloc(512 * 4);
  float*          W1cT   = (float*)alloc((size_t)512 * 1024 * 4);
  unsigned short* KmatT  = (unsigned short*)alloc((size_t)16384 * 1024 * 2);
  float*          sPart  = (float*)alloc((size_t)4 * 2048 * 96 * 4);
  int*            is_s   = (int*)alloc(2048 * 4);
  int*            is_e   = (int*)alloc(2048 * 4);
  unsigned short* UVb    = (unsigned short*)alloc((size_t)2048 * 2048 * 2);
  float*          Wsp2T  = (float*)alloc((size_t)1024 * 1024 * 4);
  float*          MmTf   = (float*)alloc((size_t)32 * 1024 * 4);
  unsigned short* MmTb   = (unsigned short*)alloc((size_t)32 * 1024 * 2);
  float*          cv     = (float*)alloc(32 * 4);
  unsigned short* W2padT = (unsigned short*)alloc((size_t)16 * 512 * 2);
  unsigned short* bsp1b  = (unsigned short*)alloc((size_t)1024 * 2);

  float* outS    = (float*)d_out;
  float* outIdx  = outS + (size_t)2048 * 32 * 3;
  float* outMask = outIdx + (size_t)NSPAN * 2;
  float* outLog  = outMask + NSPAN;

  // transposes + gather + Wtb0 in one launch
  mega0_k<<<dim3(96, 32, 8), dim3(32, 8), 0, stream>>>(
      hs, wm, we_b, Wt, W1a, Wsp1, W1c, Wsp2, WtT, W1aT, Wsp1Tc, W1cT, Wsp2T, Wtb0);

  // lab = L@Wl+bl and MmTf = L@Wsp2T
  rgemm8z_k<<<dim3(128, 4, 2), 256, 0, stream>>>(L, Wl, bl, lab, Wsp2T, MmTf);

  // kmat + BvecB + misc + bt0A in one launch
  mega1_k<<<8449, 256, 0, stream>>>(lab, W1cT, KmatT, W1b, b1, BvecB,
                                    bsp2, L, cv, MmTf, MmTb, W2, W2padT, bsp1, bsp1b,
                                    bt, W1a, bt0A);

  // WfuseT = W1aT @ Wtb0^T  (512 x 1024 bf16): Avec folding matrix
  gemm_k<3><<<dim3(8, 4), 256, 0, stream>>>(W1aT, Wtb0, 1024, 1024, nullptr, WfuseT,
                                            nullptr, nullptr, nullptr, nullptr);
  // merged: [tok | UV | Avec] = we @ [Wt | Wsp1 | Wfuse]  (N = 4608)
  gemm_k<1><<<dim3(36, 16), 256, 0, stream>>>(we_b, WtT, 4608, 1024, Avec, t0b, t1b,
                                              UVb, bt, bt0A);
  // E-GEMM (BK=64, counted vmcnt, 8x8 supertile) + fused score partials
  egemm_k<<<2048, 256, 0, stream>>>(t1b, KmatT, Avec, BvecB, W2padT, sPart);

  // fold scores + masks
  foldmask_k<<<1024, 256, 0, stream>>>(sPart, b2, outS, is_s, is_e);

  // fused span: 16 spans/wave, barrier-free, 2-step unrolled
  spanfuse_k<<<384, 256, 0, stream>>>(UVb, bsp1b, MmTb, cv, is_s, is_e,
                                      outIdx, outMask, outLog);
}

// Round 13
// 192.008 us; speedup vs baseline: 1.2176x; 1.1908x over previous
//
#include <hip/hip_runtime.h>
#include <hip/hip_bf16.h>

#define W_WORDS 2048
#define H_DIM   1024
#define C_LAB   32
#define HID_D   512
#define MAXW    12
#define NSPAN   (W_WORDS * MAXW)

typedef __attribute__((ext_vector_type(8))) short bf16x8;
typedef __attribute__((ext_vector_type(4))) float f32x4;
typedef __attribute__((ext_vector_type(4))) int i32x4;
typedef __attribute__((ext_vector_type(8))) int i32x8;

__device__ __forceinline__ unsigned short f2b(float x) {
  union { float f; unsigned int i; } v; v.f = x;
  unsigned int r = v.i + 0x7FFFu + ((v.i >> 16) & 1u);
  return (unsigned short)(r >> 16);
}
__device__ __forceinline__ float b2f(unsigned short b) {
  union { float f; unsigned int i; } v; v.i = ((unsigned int)b) << 16;
  return v.f;
}

// f32 -> OCP e4m3fn, RNE, satfinite(448)
__device__ __forceinline__ unsigned char f2e4m3(float x) {
  union { float f; unsigned u; } v; v.f = x;
  unsigned sign = (v.u >> 31) << 7;
  v.u &= 0x7FFFFFFFu;
  if (v.f > 448.f) v.f = 448.f;
  int e8 = (int)(v.u >> 23) - 120;
  unsigned r;
  if (e8 >= 1) {
    unsigned m = v.u & 0x7FFFFFu;
    unsigned keep = m >> 20;
    unsigned rest = m & 0xFFFFFu;
    keep += (rest > 0x80000u) || (rest == 0x80000u && (keep & 1u));
    if (keep == 8u) { keep = 0u; ++e8; }
    if (e8 >= 16) { e8 = 15; keep = 6u; }
    else if (e8 == 15 && keep == 7u) keep = 6u;  // avoid NaN encoding
    r = (unsigned)((e8 << 3) | keep);
  } else {
    int m = (int)(v.f * 512.f + 0.5f);
    r = (m >= 8) ? 0x08u : (unsigned)m;
  }
  return (unsigned char)(r | sign);
}

#define GLOAD_LDS16(g, l)                                                    \
  __builtin_amdgcn_global_load_lds(                                          \
      (const __attribute__((address_space(1))) unsigned int*)(g),            \
      (__attribute__((address_space(3))) unsigned int*)(l), 16, 0, 0)

// ---------- mega0: 6 transposes (z<6) + gather (z==6) + Wtb0 cvt (z==7) ----------
__global__ void mega0_k(const float* __restrict__ hs, const int* __restrict__ wm,
    unsigned short* __restrict__ we_b,
    const float* __restrict__ Wt, const float* __restrict__ W1a,
    const float* __restrict__ Wsp1, const float* __restrict__ W1c,
    const float* __restrict__ Wsp2,
    unsigned short* __restrict__ WtT, unsigned short* __restrict__ W1aT,
    unsigned short* __restrict__ Wsp1Tc, float* __restrict__ W1cT,
    float* __restrict__ Wsp2T, unsigned short* __restrict__ Wtb0) {
  if (blockIdx.z == 6) {  // gather: we_b[m-1] = bf16(hs[t])
    int t = blockIdx.y * 96 + blockIdx.x;
    int m = wm[t];
    if (m <= 0) return;
    const float* src = hs + (size_t)t * H_DIM;
    unsigned short* dst = we_b + (size_t)(m - 1) * H_DIM;
    int i = (threadIdx.y * 32 + threadIdx.x) * 4;
    float4 v = *(const float4*)(src + i);
    *(ushort4*)(dst + i) = make_ushort4(f2b(v.x), f2b(v.y), f2b(v.z), f2b(v.w));
    return;
  }
  int c0 = blockIdx.x * 32, r0 = blockIdx.y * 32;
  if (blockIdx.z == 7) {  // Wtb0[h][g] = bf16(Wt[h][g]), g<1024
    if (c0 >= 1024) return;
    for (int i = threadIdx.y; i < 32; i += 8)
      Wtb0[(size_t)(r0 + i) * 1024 + c0 + threadIdx.x] =
          f2b(Wt[(size_t)(r0 + i) * 2048 + c0 + threadIdx.x]);
    return;
  }
  const float* in;
  void* out;
  int R, C, obf;
  switch (blockIdx.z) {
    case 0: in = Wt;   out = WtT;    R = 1024; C = 2048; obf = 1; break;
    case 1: in = W1a;  out = W1aT;   R = 1024; C = 512;  obf = 1; break;
    case 2: in = Wsp1; out = Wsp1Tc; R = 1024; C = 1024; obf = 1; break;
    case 3: in = Wsp1 + 1048576; out = Wsp1Tc + 1048576; R = 1024; C = 1024; obf = 1; break;
    case 4: in = W1c;  out = W1cT;   R = 1024; C = 512;  obf = 0; break;
    default: in = Wsp2; out = Wsp2T; R = 1024; C = 1024; obf = 0; break;
  }
  if (c0 >= C || r0 >= R) return;
  __shared__ float tile[32][33];
  for (int i = threadIdx.y; i < 32; i += 8)
    tile[i][threadIdx.x] = in[(size_t)(r0 + i) * C + c0 + threadIdx.x];
  __syncthreads();
  if (obf) {
    unsigned short* o = (unsigned short*)out;
    for (int i = threadIdx.y; i < 32; i += 8)
      o[(size_t)(c0 + i) * R + r0 + threadIdx.x] = f2b(tile[threadIdx.x][i]);
  } else {
    float* o = (float*)out;
    for (int i = threadIdx.y; i < 32; i += 8)
      o[(size_t)(c0 + i) * R + r0 + threadIdx.x] = tile[threadIdx.x][i];
  }
}

// ---------- small GEMM body, 8 A-rows per block ----------
__device__ __forceinline__ void rgemm8_body(int N, int M,
    const float* __restrict__ A, int lda, const float* __restrict__ B, int ldb,
    const float* __restrict__ bias, float* __restrict__ out, int ldc,
    int bx, int by, float* shf) {
  float (*Asm)[1024] = (float(*)[1024])shf;
  float (*red)[16][8] = (float(*)[16][8])(shf + 8192);
  int m0 = by * 8;
  for (int idx = threadIdx.x; idx < 8 * 1024; idx += 256) {
    int mm = idx >> 10, kk = idx & 1023;
    Asm[mm][kk] = (m0 + mm < M) ? A[(size_t)(m0 + mm) * lda + kk] : 0.f;
  }
  __syncthreads();
  int tx = threadIdx.x & 15, ty = threadIdx.x >> 4;
  int n = bx * 16 + tx;
  float acc[8] = {0.f, 0.f, 0.f, 0.f, 0.f, 0.f, 0.f, 0.f};
  if (n < N) {
    for (int k = ty * 64; k < ty * 64 + 64; ++k) {
      float bv = B[(size_t)k * ldb + n];
#pragma unroll
      for (int mm = 0; mm < 8; ++mm) acc[mm] = fmaf(Asm[mm][k], bv, acc[mm]);
    }
  }
#pragma unroll
  for (int mm = 0; mm < 8; ++mm) red[ty][tx][mm] = acc[mm];
  __syncthreads();
  if (ty < 8 && n < N && m0 + ty < M) {
    float s = 0.f;
#pragma unroll
    for (int q = 0; q < 16; ++q) s += red[q][tx][ty];
    if (bias) s += bias[n];
    out[(size_t)(m0 + ty) * ldc + n] = s;
  }
}

// lab = L@Wl+bl (z=0) and MmTf = L@Wsp2T (z=1)
__global__ __launch_bounds__(256) void rgemm8z_k(
    const float* __restrict__ L, const float* __restrict__ Wl,
    const float* __restrict__ bl, float* __restrict__ lab,
    const float* __restrict__ Wsp2T, float* __restrict__ MmTf) {
  __shared__ float shf[10240];
  if (blockIdx.z == 0) {
    rgemm8_body(2048, 32, L, 1024, Wl, 2048, bl, lab, 2048, blockIdx.x, blockIdx.y, shf);
  } else {
    if (blockIdx.x >= 64) return;
    rgemm8_body(1024, 32, L, 1024, Wsp2T, 1024, nullptr, MmTf, 1024,
                blockIdx.x, blockIdx.y, shf);
  }
}

// ---------- mega1: kmat(fp8 x1024) + BvecB + misc + bt0A(K-parallel) ----------
__global__ __launch_bounds__(256) void mega1_k(
    const float* __restrict__ lab, const float* __restrict__ W1cT,
    unsigned char* __restrict__ KT8,
    const float* __restrict__ W1b, const float* __restrict__ b1,
    float* __restrict__ BvecB,
    const float* __restrict__ bsp2, const float* __restrict__ L,
    float* __restrict__ cv, const float* __restrict__ MmTf,
    unsigned short* __restrict__ MmTb, const float* __restrict__ W2,
    unsigned short* __restrict__ W2padT, const float* __restrict__ bsp1,
    unsigned short* __restrict__ bsp1b,
    const float* __restrict__ bt, const float* __restrict__ W1a,
    float* __restrict__ bt0A) {
  __shared__ float shf[10240];
  int g = blockIdx.x;
  if (g < 8192) {  // KT8[(c*512+d)][h] = fp8(l1[c][h] * W1c[h][d] * 1024), 8 h/thread
    size_t gid = (size_t)g * 256 + threadIdx.x;
    int row = (int)(gid >> 7);
    int h0 = ((int)gid & 127) * 8;
    int c = row >> 9, d = row & 511;
    const float* lp = lab + (size_t)c * 2048 + 1024 + h0;
    const float* wp = W1cT + (size_t)d * 1024 + h0;
    float4 l0 = *(const float4*)lp, l1 = *(const float4*)(lp + 4);
    float4 w0 = *(const float4*)wp, w1 = *(const float4*)(wp + 4);
    unsigned u0 = (unsigned)f2e4m3(l0.x * w0.x * 1024.f)
                | ((unsigned)f2e4m3(l0.y * w0.y * 1024.f) << 8)
                | ((unsigned)f2e4m3(l0.z * w0.z * 1024.f) << 16)
                | ((unsigned)f2e4m3(l0.w * w0.w * 1024.f) << 24);
    unsigned u1 = (unsigned)f2e4m3(l1.x * w1.x * 1024.f)
                | ((unsigned)f2e4m3(l1.y * w1.y * 1024.f) << 8)
                | ((unsigned)f2e4m3(l1.z * w1.z * 1024.f) << 16)
                | ((unsigned)f2e4m3(l1.w * w1.w * 1024.f) << 24);
    *(uint2*)(KT8 + (size_t)row * 1024 + h0) = make_uint2(u0, u1);
  } else if (g < 8320) {  // BvecB = l0 @ W1b + b1   (32 x 512)
    int b = g - 8192;
    rgemm8_body(512, 32, lab, 2048, W1b, 512, b1, BvecB, 512, b & 31, b >> 5, shf);
  } else {
    int b = g - 8320;
    if (b < 32) {  // cv[c] = dot(bsp2, L[c])
      int c = b;
      float a = 0.f;
      for (int k = threadIdx.x; k < 1024; k += 256)
        a = fmaf(bsp2[k], L[(size_t)c * 1024 + k], a);
#pragma unroll
      for (int off = 32; off; off >>= 1) a += __shfl_down(a, off);
      if ((threadIdx.x & 63) == 0) shf[threadIdx.x >> 6] = a;
      __syncthreads();
      if (threadIdx.x == 0) cv[c] = shf[0] + shf[1] + shf[2] + shf[3];
    } else if (b < 64) {  // MmTf -> MmTb bf16
      int i = (b - 32) * 1024 + threadIdx.x * 4;
      float4 v = *(const float4*)(MmTf + i);
      *(ushort4*)(MmTb + i) = make_ushort4(f2b(v.x), f2b(v.y), f2b(v.z), f2b(v.w));
    } else if (b < 96) {  // W2padT[n][d] = n<3 ? W2[d][n] : 0
      int i = (b - 64) * 256 + threadIdx.x;
      int n = i >> 9, d = i & 511;
      W2padT[i] = f2b(n < 3 ? W2[d * 3 + n] : 0.f);
    } else if (b == 96) {  // bsp1 -> bsp1b bf16
      int i = threadIdx.x * 4;
      float4 v = *(const float4*)(bsp1 + i);
      *(ushort4*)(bsp1b + i) = make_ushort4(f2b(v.x), f2b(v.y), f2b(v.z), f2b(v.w));
    } else {  // b in [97,129): bt0A[d] = dot(bt[0:1024], W1a[:,d]), K-parallel
      float (*red)[16] = (float(*)[16])shf;
      int tx = threadIdx.x & 15, ty = threadIdx.x >> 4;
      int d = (b - 97) * 16 + tx;
      float a = 0.f;
      for (int k = ty * 64; k < ty * 64 + 64; ++k)
        a = fmaf(bt[k], W1a[(size_t)k * 512 + d], a);
      red[ty][tx] = a;
      __syncthreads();
      if (ty == 0) {
        float s = 0.f;
#pragma unroll
        for (int q = 0; q < 16; ++q) s += red[q][tx];
        bt0A[d] = s;
      }
    }
  }
}

// ---------- bf16 MFMA GEMM, 128x128 tile, BK=64, counted-vmcnt dbuf ----------
// MODE 1: merged N=3584: c<1024 -> t1f8 (fp8 x16, bias bt[1024+c]);
//         <3072 -> out2 bf16 (UVb ld 2048); else Avec f32 = v + bias2[c-3072]
// MODE 3: out0 bf16 full tile (ld N)
template <int MODE>
__global__ __launch_bounds__(256) void gemm_k(
    const unsigned short* __restrict__ A, const unsigned short* __restrict__ BT,
    int N, int K,
    float* __restrict__ outF,
    unsigned short* __restrict__ out0, unsigned char* __restrict__ out8,
    unsigned short* __restrict__ out2,
    const float* __restrict__ bias, const float* __restrict__ bias2) {
  __shared__ __align__(16) unsigned short smem[2][16384];  // 64 KB dbuf
  int tid = threadIdx.x;
  int lane = tid & 63, wid = tid >> 6;
  int wr = wid >> 1, wc = wid & 1;
  int row0 = blockIdx.y * 128, col0 = blockIdx.x * 128;

  f32x4 zero4 = {0.f, 0.f, 0.f, 0.f};
  f32x4 acc[4][4];
#pragma unroll
  for (int i = 0; i < 4; ++i)
#pragma unroll
    for (int j = 0; j < 4; ++j) acc[i][j] = zero4;

  int srow = tid >> 3;
  int scol = ((tid & 7) ^ (srow & 7)) * 8;  // pre-swizzled global source
  const unsigned short* gA = A + (size_t)(row0 + srow) * K + scol;
  const unsigned short* gB = BT + (size_t)(col0 + srow) * K + scol;

  int fr = lane & 15, hi = lane >> 4;

#define G_STAGE(buf, kt)                                                     \
  {                                                                          \
    unsigned short* dA = smem[buf] + tid * 8;                                \
    unsigned short* dB = smem[buf] + 8192 + tid * 8;                         \
    _Pragma("unroll")                                                        \
    for (int i2 = 0; i2 < 4; ++i2) {                                         \
      GLOAD_LDS16(gA + (size_t)(i2 * 32) * K + (kt), dA + i2 * 2048);        \
      GLOAD_LDS16(gB + (size_t)(i2 * 32) * K + (kt), dB + i2 * 2048);        \
    }                                                                        \
  }

  G_STAGE(0, 0);

  int nt = K >> 6;
  for (int t = 0; t < nt; ++t) {
    if (t + 1 < nt) {
      G_STAGE((t + 1) & 1, (t + 1) << 6);
      asm volatile("s_waitcnt vmcnt(8)" ::: "memory");
    } else {
      asm volatile("s_waitcnt vmcnt(0)" ::: "memory");
    }
    __builtin_amdgcn_sched_barrier(0);
    __builtin_amdgcn_s_barrier();
    __builtin_amdgcn_sched_barrier(0);

    const unsigned short* As = smem[t & 1];
    const unsigned short* Bs = smem[t & 1] + 8192;
    bf16x8 af[4][2], bfr[4][2];
#pragma unroll
    for (int mi = 0; mi < 4; ++mi) {
      int rl = wr * 64 + mi * 16 + fr;
#pragma unroll
      for (int kk = 0; kk < 2; ++kk)
        af[mi][kk] = *(const bf16x8*)&As[rl * 64 + (((kk << 2) | hi) ^ (rl & 7)) * 8];
    }
#pragma unroll
    for (int ni = 0; ni < 4; ++ni) {
      int rl = wc * 64 + ni * 16 + fr;
#pragma unroll
      for (int kk = 0; kk < 2; ++kk)
        bfr[ni][kk] = *(const bf16x8*)&Bs[rl * 64 + (((kk << 2) | hi) ^ (rl & 7)) * 8];
    }
#pragma unroll
    for (int kk = 0; kk < 2; ++kk)
#pragma unroll
      for (int mi = 0; mi < 4; ++mi)
#pragma unroll
        for (int ni = 0; ni < 4; ++ni)
          acc[mi][ni] = __builtin_amdgcn_mfma_f32_16x16x32_bf16(af[mi][kk], bfr[ni][kk],
                                                                acc[mi][ni], 0, 0, 0);
    __builtin_amdgcn_sched_barrier(0);
    __builtin_amdgcn_s_barrier();
  }
#undef G_STAGE

  int rbase = row0 + wr * 64 + (hi << 2);
  int cbase = col0 + wc * 64 + fr;
#pragma unroll
  for (int mi = 0; mi < 4; ++mi) {
#pragma unroll
    for (int ni = 0; ni < 4; ++ni) {
      int ccol = cbase + ni * 16;
#pragma unroll
      for (int j = 0; j < 4; ++j) {
        int r = rbase + mi * 16 + j;
        float v = acc[mi][ni][j];
        if (MODE == 3) {
          out0[(size_t)r * N + ccol] = f2b(v);
        } else {
          if (ccol < 1024) {
            out8[(size_t)r * 1024 + ccol] = f2e4m3((v + bias[1024 + ccol]) * 16.f);
          } else if (ccol < 3072) {
            out2[(size_t)r * 2048 + (ccol - 1024)] = f2b(v);
          } else {
            outF[(size_t)r * 512 + (ccol - 3072)] = v + bias2[ccol - 3072];
          }
        }
      }
    }
  }
}

// ---------- E-GEMM: 128² tile, MX-fp8 K=128, counted-vmcnt dbuf, supertile ----------
// h = relu(acc*2^-14 + avec + bvec) -> swizzled LDS -> MFMA vs W2padT -> sPart.
__global__ __launch_bounds__(256) void egemm_k(
    const unsigned char* __restrict__ A,   // t1f8 [2048][1024] (x16 pre-scaled)
    const unsigned char* __restrict__ BT,  // KT8 [16384][1024] (x1024 pre-scaled)
    const float* __restrict__ avec, const float* __restrict__ bvec,
    const unsigned short* __restrict__ w2t, float* __restrict__ sPart) {
  __shared__ __align__(16) unsigned char smem[2][32768];  // 64 KB dbuf (A 16K | B 16K)
  int tid = threadIdx.x;
  int lane = tid & 63, wid = tid >> 6;
  int wr = wid >> 1, wc = wid & 1;
  // 8 xcd x (2x2 supergrid of 8rb x 8cb supertiles)
  int bid = blockIdx.x;
  int xcd = bid & 7, ii = bid >> 3;
  int sg = ii >> 6, inner = ii & 63;
  int rb = ((sg >> 1) << 3) | (inner & 7);
  int cb = xcd * 16 + (((sg & 1) << 3) | (inner >> 3));
  int row0 = rb * 128, col0 = cb * 128, cbq = cb & 3;

  f32x4 zero4 = {0.f, 0.f, 0.f, 0.f};
  f32x4 acc[4][4];
#pragma unroll
  for (int i = 0; i < 4; ++i)
#pragma unroll
    for (int j = 0; j < 4; ++j) acc[i][j] = zero4;

  // staging: rows of 128 B = 8 slots x 16 B; phys slot = log ^ (row&7)
  int srow = tid >> 3;
  int scolB = ((tid & 7) ^ (srow & 7)) * 16;
  const unsigned char* gA = A + (size_t)(row0 + srow) * 1024 + scolB;
  const unsigned char* gB = BT + (size_t)(col0 + srow) * 1024 + scolB;

  int fr = lane & 15, hi = lane >> 4;

#define E_STAGE(buf, ktB)                                                    \
  {                                                                          \
    unsigned char* dA = smem[buf] + tid * 16;                                \
    unsigned char* dB = smem[buf] + 16384 + tid * 16;                        \
    _Pragma("unroll")                                                        \
    for (int i2 = 0; i2 < 4; ++i2) {                                         \
      GLOAD_LDS16(gA + (size_t)(i2 * 32) * 1024 + (ktB), dA + i2 * 4096);    \
      GLOAD_LDS16(gB + (size_t)(i2 * 32) * 1024 + (ktB), dB + i2 * 4096);    \
    }                                                                        \
  }

  E_STAGE(0, 0);

  for (int t = 0; t < 8; ++t) {
    if (t + 1 < 8) {
      E_STAGE((t + 1) & 1, (t + 1) * 128);
      asm volatile("s_waitcnt vmcnt(8)" ::: "memory");
    } else {
      asm volatile("s_waitcnt vmcnt(0)" ::: "memory");
    }
    __builtin_amdgcn_sched_barrier(0);
    __builtin_amdgcn_s_barrier();
    __builtin_amdgcn_sched_barrier(0);

    const unsigned char* As = smem[t & 1];
    const unsigned char* Bs = smem[t & 1] + 16384;
    i32x8 af[4], bfr[4];
#pragma unroll
    for (int mi = 0; mi < 4; ++mi) {
      int rl = wr * 64 + mi * 16 + fr;
      i32x4 lo = *(const i32x4*)&As[rl * 128 + (((2 * hi) ^ (rl & 7)) * 16)];
      i32x4 h2 = *(const i32x4*)&As[rl * 128 + (((2 * hi + 1) ^ (rl & 7)) * 16)];
      af[mi][0] = lo[0]; af[mi][1] = lo[1]; af[mi][2] = lo[2]; af[mi][3] = lo[3];
      af[mi][4] = h2[0]; af[mi][5] = h2[1]; af[mi][6] = h2[2]; af[mi][7] = h2[3];
    }
#pragma unroll
    for (int ni = 0; ni < 4; ++ni) {
      int rl = wc * 64 + ni * 16 + fr;
      i32x4 lo = *(const i32x4*)&Bs[rl * 128 + (((2 * hi) ^ (rl & 7)) * 16)];
      i32x4 h2 = *(const i32x4*)&Bs[rl * 128 + (((2 * hi + 1) ^ (rl & 7)) * 16)];
      bfr[ni][0] = lo[0]; bfr[ni][1] = lo[1]; bfr[ni][2] = lo[2]; bfr[ni][3] = lo[3];
      bfr[ni][4] = h2[0]; bfr[ni][5] = h2[1]; bfr[ni][6] = h2[2]; bfr[ni][7] = h2[3];
    }
#pragma unroll
    for (int mi = 0; mi < 4; ++mi)
#pragma unroll
      for (int ni = 0; ni < 4; ++ni)
        acc[mi][ni] = __builtin_amdgcn_mfma_scale_f32_16x16x128_f8f6f4(
            af[mi], bfr[ni], acc[mi][ni], 0, 0, 0, 127u, 0, 127u);
    __builtin_amdgcn_sched_barrier(0);
    __builtin_amdgcn_s_barrier();
  }
#undef E_STAGE

  // ---- epilogue: h -> swizzled LDS (32 KB of smem[0]) -> W2 MFMA ----
  unsigned short* hsm = (unsigned short*)&smem[0][0];
  int cc = col0 >> 9;
  int dg0 = col0 & 511;
  const float inv = 6.103515625e-05f;  // 2^-14 undo pre-scales (16 * 1024)
#pragma unroll
  for (int mi = 0; mi < 4; ++mi) {
#pragma unroll
    for (int j = 0; j < 4; ++j) {
      int rl = wr * 64 + hi * 4 + mi * 16 + j;
      const float* avp = avec + (size_t)(row0 + rl) * 512 + dg0;
      const float* bvp = bvec + (size_t)cc * 512 + dg0;
#pragma unroll
      for (int ni = 0; ni < 4; ++ni) {
        int cl = wc * 64 + ni * 16 + fr;
        float v = acc[mi][ni][j] * inv + avp[cl] + bvp[cl];
        v = fmaxf(v, 0.f);
        int slot = cl >> 3;
        hsm[rl * 128 + (((slot ^ rl) & 7) << 3) + (slot & 8) * 8 + (cl & 7)] = f2b(v);
      }
    }
  }
  __syncthreads();
  f32x4 s0 = zero4, s1 = zero4;
  int r0l = wid * 32 + fr;
  int r1l = wid * 32 + 16 + fr;
#pragma unroll
  for (int kt2 = 0; kt2 < 4; ++kt2) {
    int slot = kt2 * 4 + hi;
    bf16x8 a0 = *(const bf16x8*)&hsm[r0l * 128 + (((slot ^ r0l) & 7) << 3) + (slot & 8) * 8];
    bf16x8 a1 = *(const bf16x8*)&hsm[r1l * 128 + (((slot ^ r1l) & 7) << 3) + (slot & 8) * 8];
    bf16x8 b = *(const bf16x8*)&w2t[(size_t)fr * 512 + dg0 + kt2 * 32 + hi * 8];
    s0 = __builtin_amdgcn_mfma_f32_16x16x32_bf16(a0, b, s0, 0, 0, 0);
    s1 = __builtin_amdgcn_mfma_f32_16x16x32_bf16(a1, b, s1, 0, 0, 0);
  }
  if (fr < 3) {
    float* sp = sPart + ((size_t)cbq * 2048 + row0) * 96 + cc * 3 + fr;
#pragma unroll
    for (int j = 0; j < 4; ++j) {
      sp[(size_t)(wid * 32 + hi * 4 + j) * 96] = s0[j];
      sp[(size_t)(wid * 32 + 16 + hi * 4 + j) * 96] = s1[j];
    }
  }
}

// ---------- fold 4 score slices + b2, then is_start/is_end ----------
__global__ __launch_bounds__(256) void foldmask_k(const float* __restrict__ part,
    const float* __restrict__ b2, float* __restrict__ outS,
    int* __restrict__ is_s, int* __restrict__ is_e) {
  __shared__ float sc[192];
  int b = blockIdx.x;
  int i = threadIdx.x;
  if (i < 192) {
    int idx = b * 192 + i;
    float s = b2[i % 3] + part[idx] + part[196608 + idx] +
              part[2 * 196608 + idx] + part[3 * 196608 + idx];
    outS[idx] = s;
    sc[i] = s;
  }
  __syncthreads();
  if (i < 2) {
    int s = 0, e = 0;
#pragma unroll
    for (int c = 0; c < 32; ++c) {
      s |= (sc[i * 96 + c * 3 + 0] >= 0.f);
      e |= (sc[i * 96 + c * 3 + 1] >= 0.f);
    }
    is_s[2 * b + i] = s;
    is_e[2 * b + i] = e;
  }
}

// ---------- fused span: 16 spans/wave, barrier-free, 2-step unrolled ----------
__global__ __launch_bounds__(256) void spanfuse_k(
    const unsigned short* __restrict__ UVb, const unsigned short* __restrict__ bsp1b,
    const unsigned short* __restrict__ MmTb, const float* __restrict__ cvv,
    const int* __restrict__ is_s, const int* __restrict__ is_e,
    float* __restrict__ outIdx, float* __restrict__ outMask,
    float* __restrict__ outLog) {
  __shared__ __align__(16) unsigned short Rs[4][2][16][32];  // 8 KB
  int tid = threadIdx.x, lane = tid & 63, w = tid >> 6;
  int fr = lane & 15, hi = lane >> 4;
  int row = lane >> 2, q = lane & 3;
  int n = blockIdx.x * 64 + w * 16 + row;
  int wi = n / MAXW;
  int j = n - wi * MAXW;
  int er = wi + j;
  int valid = er < W_WORDS;
  int e = valid ? er : (W_WORDS - 1);
  int mask = (valid && is_s[wi] && is_e[e]) ? 1 : 0;
  if (q == 0) {
    outIdx[2 * n] = (float)wi;
    outIdx[2 * n + 1] = (float)e;
    outMask[n] = (float)mask;
  }
  int si = mask ? wi : 0, ei = mask ? e : 0;
  const unsigned short* Up = UVb + (size_t)si * 2048 + q * 8;
  const unsigned short* Vp = UVb + (size_t)ei * 2048 + 1024 + q * 8;
  const unsigned short* bp = bsp1b + q * 8;
  const unsigned short* M0 = MmTb + (size_t)fr * 1024 + hi * 8;
  const unsigned short* M1 = MmTb + (size_t)(16 + fr) * 1024 + hi * 8;
  unsigned short* wRs0 = &Rs[w][0][0][0];
  unsigned short* wRs1 = &Rs[w][1][0][0];
  int wslot = (q ^ (row & 3)) * 8;
  int rslot = ((hi ^ (fr & 3)) & 3) * 8;
  f32x4 zero4 = {0.f, 0.f, 0.f, 0.f};
  f32x4 a0 = zero4, a1 = zero4;

  bf16x8 u0 = *(const bf16x8*)Up,        v0 = *(const bf16x8*)Vp;
  bf16x8 b0 = *(const bf16x8*)bp;
  bf16x8 u1 = *(const bf16x8*)(Up + 32), v1 = *(const bf16x8*)(Vp + 32);
  bf16x8 b1v = *(const bf16x8*)(bp + 32);
  bf16x8 f00 = *(const bf16x8*)M0,        f10 = *(const bf16x8*)M1;
  bf16x8 f01 = *(const bf16x8*)(M0 + 32), f11 = *(const bf16x8*)(M1 + 32);

  for (int kt = 0; kt < 32; kt += 2) {
    int ka = ((kt + 2) & 31) * 32, kb = ((kt + 3) & 31) * 32;
    bf16x8 nu0 = *(const bf16x8*)(Up + ka), nv0 = *(const bf16x8*)(Vp + ka);
    bf16x8 nb0 = *(const bf16x8*)(bp + ka);
    bf16x8 nu1 = *(const bf16x8*)(Up + kb), nv1 = *(const bf16x8*)(Vp + kb);
    bf16x8 nb1 = *(const bf16x8*)(bp + kb);
    bf16x8 nf00 = *(const bf16x8*)(M0 + ka), nf10 = *(const bf16x8*)(M1 + ka);
    bf16x8 nf01 = *(const bf16x8*)(M0 + kb), nf11 = *(const bf16x8*)(M1 + kb);

    bf16x8 o0, o1;
#pragma unroll
    for (int i = 0; i < 8; ++i) {
      o0[i] = (short)f2b(fmaxf(b2f((unsigned short)u0[i]) + b2f((unsigned short)v0[i]) +
                               b2f((unsigned short)b0[i]), 0.f));
      o1[i] = (short)f2b(fmaxf(b2f((unsigned short)u1[i]) + b2f((unsigned short)v1[i]) +
                               b2f((unsigned short)b1v[i]), 0.f));
    }
    *(bf16x8*)&wRs0[row * 32 + wslot] = o0;
    *(bf16x8*)&wRs1[row * 32 + wslot] = o1;
    asm volatile("s_waitcnt lgkmcnt(0)" ::: "memory");
    bf16x8 fa0 = *(const bf16x8*)&wRs0[fr * 32 + rslot];
    bf16x8 fa1 = *(const bf16x8*)&wRs1[fr * 32 + rslot];
    a0 = __builtin_amdgcn_mfma_f32_16x16x32_bf16(fa0, f00, a0, 0, 0, 0);
    a1 = __builtin_amdgcn_mfma_f32_16x16x32_bf16(fa0, f10, a1, 0, 0, 0);
    a0 = __builtin_amdgcn_mfma_f32_16x16x32_bf16(fa1, f01, a0, 0, 0, 0);
    a1 = __builtin_amdgcn_mfma_f32_16x16x32_bf16(fa1, f11, a1, 0, 0, 0);
    u0 = nu0; v0 = nv0; b0 = nb0;
    u1 = nu1; v1 = nv1; b1v = nb1;
    f00 = nf00; f10 = nf10; f01 = nf01; f11 = nf11;
  }

  int n0 = blockIdx.x * 64 + w * 16;
  float c0 = cvv[fr], c1 = cvv[16 + fr];
#pragma unroll
  for (int jj = 0; jj < 4; ++jj) {
    int nn = n0 + hi * 4 + jj;
    outLog[(size_t)nn * 32 + fr] = a0[jj] + c0;
    outLog[(size_t)nn * 32 + 16 + fr] = a1[jj] + c1;
  }
}

extern "C" void kernel_launch(void* const* d_in, const int* in_sizes, int n_in,
                              void* d_out, int out_size, void* d_ws, size_t ws_size,
                              hipStream_t stream) {
  const float* hs   = (const float*)d_in[0];
  const int*   wm   = (const int*)d_in[1];
  const float* L    = (const float*)d_in[2];
  const float* Wt   = (const float*)d_in[3];
  const float* bt   = (const float*)d_in[4];
  const float* Wl   = (const float*)d_in[5];
  const float* bl   = (const float*)d_in[6];
  const float* W1a  = (const float*)d_in[7];
  const float* W1b  = (const float*)d_in[8];
  const float* W1c  = (const float*)d_in[9];
  const float* b1   = (const float*)d_in[10];
  const float* W2   = (const float*)d_in[11];
  const float* b2   = (const float*)d_in[12];
  const float* Wsp1 = (const float*)d_in[13];
  const float* bsp1 = (const float*)d_in[14];
  const float* Wsp2 = (const float*)d_in[15];
  const float* bsp2 = (const float*)d_in[16];

  char* p = (char*)d_ws;
  auto alloc = [&p](size_t bytes) {
    char* r = p;
    p += (bytes + 255) & ~(size_t)255;
    return r;
  };
  unsigned short* we_b   = (unsigned short*)alloc((size_t)2048 * 1024 * 2);
  // WtT, Wsp1Tc, WfuseT MUST be adjacent: merged BT = WtT+1024*1024 (3584 x 1024)
  unsigned short* WtT    = (unsigned short*)alloc((size_t)2048 * 1024 * 2);
  unsigned short* Wsp1Tc = (unsigned short*)alloc((size_t)2048 * 1024 * 2);
  unsigned short* WfuseT = (unsigned short*)alloc((size_t)512 * 1024 * 2);
  unsigned char*  t1f8   = (unsigned char*)alloc((size_t)2048 * 1024);
  float*          lab    = (float*)alloc((size_t)32 * 2048 * 4);
  unsigned short* W1aT   = (unsigned short*)alloc((size_t)512 * 1024 * 2);
  unsigned short* Wtb0   = (unsigned short*)alloc((size_t)1024 * 1024 * 2);
  float*          Avec   = (float*)alloc((size_t)2048 * 512 * 4);
  float*          BvecB  = (float*)alloc((size_t)32 * 512 * 4);
  float*          bt0A   = (float*)alloc(512 * 4);
  float*          W1cT   = (float*)alloc((size_t)512 * 1024 * 4);
  unsigned char*  KT8    = (unsigned char*)alloc((size_t)16384 * 1024);
  float*          sPart  = (float*)alloc((size_t)4 * 2048 * 96 * 4);
  int*            is_s   = (int*)alloc(2048 * 4);
  int*            is_e   = (int*)alloc(2048 * 4);
  unsigned short* UVb    = (unsigned short*)alloc((size_t)2048 * 2048 * 2);
  float*          Wsp2T  = (float*)alloc((size_t)1024 * 1024 * 4);
  float*          MmTf   = (float*)alloc((size_t)32 * 1024 * 4);
  unsigned short* MmTb   = (unsigned short*)alloc((size_t)32 * 1024 * 2);
  float*          cv     = (float*)alloc(32 * 4);
  unsigned short* W2padT = (unsigned short*)alloc((size_t)16 * 512 * 2);
  unsigned short* bsp1b  = (unsigned short*)alloc((size_t)1024 * 2);

  float* outS    = (float*)d_out;
  float* outIdx  = outS + (size_t)2048 * 32 * 3;
  float* outMask = outIdx + (size_t)NSPAN * 2;
  float* outLog  = outMask + NSPAN;

  // transposes + gather + Wtb0 in one launch
  mega0_k<<<dim3(96, 32, 8), dim3(32, 8), 0, stream>>>(
      hs, wm, we_b, Wt, W1a, Wsp1, W1c, Wsp2, WtT, W1aT, Wsp1Tc, W1cT, Wsp2T, Wtb0);

  // lab = L@Wl+bl and MmTf = L@Wsp2T
  rgemm8z_k<<<dim3(128, 4, 2), 256, 0, stream>>>(L, Wl, bl, lab, Wsp2T, MmTf);

  // kmat(fp8) + BvecB + misc + bt0A in one launch
  mega1_k<<<8449, 256, 0, stream>>>(lab, W1cT, KT8, W1b, b1, BvecB,
                                    bsp2, L, cv, MmTf, MmTb, W2, W2padT, bsp1, bsp1b,
                                    bt, W1a, bt0A);

  // WfuseT = W1aT @ Wtb0^T  (512 x 1024 bf16): Avec folding matrix
  gemm_k<3><<<dim3(8, 4), 256, 0, stream>>>(W1aT, Wtb0, 1024, 1024, nullptr, WfuseT,
                                            nullptr, nullptr, nullptr, nullptr);
  // merged: [t1 | UV | Avec] = we @ [Wt_hi | Wsp1 | Wfuse]  (N = 3584)
  gemm_k<1><<<dim3(28, 16), 256, 0, stream>>>(we_b, WtT + (size_t)1024 * 1024, 3584, 1024,
                                              Avec, nullptr, t1f8, UVb, bt, bt0A);
  // E-GEMM (MX-fp8 K=128, counted vmcnt, supertile) + fused score partials
  egemm_k<<<2048, 256, 0, stream>>>(t1f8, KT8, Avec, BvecB, W2padT, sPart);

  // fold scores + masks
  foldmask_k<<<1024, 256, 0, stream>>>(sPart, b2, outS, is_s, is_e);

  // fused span: 16 spans/wave, barrier-free, 2-step unrolled
  spanfuse_k<<<384, 256, 0, stream>>>(UVb, bsp1b, MmTb, cv, is_s, is_e,
                                      outIdx, outMask, outLog);
}

// Round 14
// 191.723 us; speedup vs baseline: 1.2194x; 1.0015x over previous
//
#include <hip/hip_runtime.h>
#include <hip/hip_bf16.h>

#define W_WORDS 2048
#define H_DIM   1024
#define C_LAB   32
#define HID_D   512
#define MAXW    12
#define NSPAN   (W_WORDS * MAXW)

typedef __attribute__((ext_vector_type(8))) short bf16x8;
typedef __attribute__((ext_vector_type(4))) float f32x4;
typedef __attribute__((ext_vector_type(4))) int i32x4;
typedef __attribute__((ext_vector_type(8))) int i32x8;

__device__ __forceinline__ unsigned short f2b(float x) {
  union { float f; unsigned int i; } v; v.f = x;
  unsigned int r = v.i + 0x7FFFu + ((v.i >> 16) & 1u);
  return (unsigned short)(r >> 16);
}
__device__ __forceinline__ float b2f(unsigned short b) {
  union { float f; unsigned int i; } v; v.i = ((unsigned int)b) << 16;
  return v.f;
}

// f32 -> OCP e4m3fn, RNE, satfinite(448)
__device__ __forceinline__ unsigned char f2e4m3(float x) {
  union { float f; unsigned u; } v; v.f = x;
  unsigned sign = (v.u >> 31) << 7;
  v.u &= 0x7FFFFFFFu;
  if (v.f > 448.f) v.f = 448.f;
  int e8 = (int)(v.u >> 23) - 120;
  unsigned r;
  if (e8 >= 1) {
    unsigned m = v.u & 0x7FFFFFu;
    unsigned keep = m >> 20;
    unsigned rest = m & 0xFFFFFu;
    keep += (rest > 0x80000u) || (rest == 0x80000u && (keep & 1u));
    if (keep == 8u) { keep = 0u; ++e8; }
    if (e8 >= 16) { e8 = 15; keep = 6u; }
    else if (e8 == 15 && keep == 7u) keep = 6u;  // avoid NaN encoding
    r = (unsigned)((e8 << 3) | keep);
  } else {
    int m = (int)(v.f * 512.f + 0.5f);
    r = (m >= 8) ? 0x08u : (unsigned)m;
  }
  return (unsigned char)(r | sign);
}

#define GLOAD_LDS16(g, l)                                                    \
  __builtin_amdgcn_global_load_lds(                                          \
      (const __attribute__((address_space(1))) unsigned int*)(g),            \
      (__attribute__((address_space(3))) unsigned int*)(l), 16, 0, 0)

// ---------- mega0: transposes (z<6) + gather fp8 (z==6) + Wtb0 cvt (z==7) ----------
// z0: Wt_hi -> fp8 x64; z1: W1a -> bf16; z2/z3: Wsp1 halves -> fp8 x64;
// z4: W1c f32; z5: Wsp2 f32
__global__ void mega0_k(const float* __restrict__ hs, const int* __restrict__ wm,
    unsigned char* __restrict__ we8,
    const float* __restrict__ Wt, const float* __restrict__ W1a,
    const float* __restrict__ Wsp1, const float* __restrict__ W1c,
    const float* __restrict__ Wsp2,
    unsigned char* __restrict__ WtT8, unsigned short* __restrict__ W1aT,
    unsigned char* __restrict__ Wsp1Tc8, float* __restrict__ W1cT,
    float* __restrict__ Wsp2T, unsigned short* __restrict__ Wtb0) {
  if (blockIdx.z == 6) {  // gather: we8[m-1] = fp8(hs[t] * 16)
    int t = blockIdx.y * 96 + blockIdx.x;
    int m = wm[t];
    if (m <= 0) return;
    const float* src = hs + (size_t)t * H_DIM;
    unsigned char* dst = we8 + (size_t)(m - 1) * H_DIM;
    int i = (threadIdx.y * 32 + threadIdx.x) * 4;
    float4 v = *(const float4*)(src + i);
    unsigned u = (unsigned)f2e4m3(v.x * 16.f)
               | ((unsigned)f2e4m3(v.y * 16.f) << 8)
               | ((unsigned)f2e4m3(v.z * 16.f) << 16)
               | ((unsigned)f2e4m3(v.w * 16.f) << 24);
    *(unsigned*)(dst + i) = u;
    return;
  }
  int c0 = blockIdx.x * 32, r0 = blockIdx.y * 32;
  if (blockIdx.z == 7) {  // Wtb0[h][g] = bf16(Wt[h][g]), g<1024
    if (c0 >= 1024) return;
    for (int i = threadIdx.y; i < 32; i += 8)
      Wtb0[(size_t)(r0 + i) * 1024 + c0 + threadIdx.x] =
          f2b(Wt[(size_t)(r0 + i) * 2048 + c0 + threadIdx.x]);
    return;
  }
  const float* in;
  void* out;
  int R, C, ld, mode;  // mode: 0=f32, 1=bf16, 2=fp8 x64
  switch (blockIdx.z) {
    case 0: in = Wt + 1024; out = WtT8; R = 1024; C = 1024; ld = 2048; mode = 2; break;
    case 1: in = W1a;  out = W1aT;   R = 1024; C = 512;  ld = 512;  mode = 1; break;
    case 2: in = Wsp1; out = Wsp1Tc8; R = 1024; C = 1024; ld = 1024; mode = 2; break;
    case 3: in = Wsp1 + 1048576; out = Wsp1Tc8 + 1048576; R = 1024; C = 1024; ld = 1024; mode = 2; break;
    case 4: in = W1c;  out = W1cT;   R = 1024; C = 512;  ld = 512;  mode = 0; break;
    default: in = Wsp2; out = Wsp2T; R = 1024; C = 1024; ld = 1024; mode = 0; break;
  }
  if (c0 >= C || r0 >= R) return;
  __shared__ float tile[32][33];
  for (int i = threadIdx.y; i < 32; i += 8)
    tile[i][threadIdx.x] = in[(size_t)(r0 + i) * ld + c0 + threadIdx.x];
  __syncthreads();
  if (mode == 2) {
    unsigned char* o = (unsigned char*)out;
    for (int i = threadIdx.y; i < 32; i += 8)
      o[(size_t)(c0 + i) * R + r0 + threadIdx.x] = f2e4m3(tile[threadIdx.x][i] * 64.f);
  } else if (mode == 1) {
    unsigned short* o = (unsigned short*)out;
    for (int i = threadIdx.y; i < 32; i += 8)
      o[(size_t)(c0 + i) * R + r0 + threadIdx.x] = f2b(tile[threadIdx.x][i]);
  } else {
    float* o = (float*)out;
    for (int i = threadIdx.y; i < 32; i += 8)
      o[(size_t)(c0 + i) * R + r0 + threadIdx.x] = tile[threadIdx.x][i];
  }
}

// ---------- small GEMM body, 8 A-rows per block ----------
__device__ __forceinline__ void rgemm8_body(int N, int M,
    const float* __restrict__ A, int lda, const float* __restrict__ B, int ldb,
    const float* __restrict__ bias, float* __restrict__ out, int ldc,
    int bx, int by, float* shf) {
  float (*Asm)[1024] = (float(*)[1024])shf;
  float (*red)[16][8] = (float(*)[16][8])(shf + 8192);
  int m0 = by * 8;
  for (int idx = threadIdx.x; idx < 8 * 1024; idx += 256) {
    int mm = idx >> 10, kk = idx & 1023;
    Asm[mm][kk] = (m0 + mm < M) ? A[(size_t)(m0 + mm) * lda + kk] : 0.f;
  }
  __syncthreads();
  int tx = threadIdx.x & 15, ty = threadIdx.x >> 4;
  int n = bx * 16 + tx;
  float acc[8] = {0.f, 0.f, 0.f, 0.f, 0.f, 0.f, 0.f, 0.f};
  if (n < N) {
    for (int k = ty * 64; k < ty * 64 + 64; ++k) {
      float bv = B[(size_t)k * ldb + n];
#pragma unroll
      for (int mm = 0; mm < 8; ++mm) acc[mm] = fmaf(Asm[mm][k], bv, acc[mm]);
    }
  }
#pragma unroll
  for (int mm = 0; mm < 8; ++mm) red[ty][tx][mm] = acc[mm];
  __syncthreads();
  if (ty < 8 && n < N && m0 + ty < M) {
    float s = 0.f;
#pragma unroll
    for (int q = 0; q < 16; ++q) s += red[q][tx][ty];
    if (bias) s += bias[n];
    out[(size_t)(m0 + ty) * ldc + n] = s;
  }
}

// lab = L@Wl+bl (z=0) and MmTf = L@Wsp2T (z=1)
__global__ __launch_bounds__(256) void rgemm8z_k(
    const float* __restrict__ L, const float* __restrict__ Wl,
    const float* __restrict__ bl, float* __restrict__ lab,
    const float* __restrict__ Wsp2T, float* __restrict__ MmTf) {
  __shared__ float shf[10240];
  if (blockIdx.z == 0) {
    rgemm8_body(2048, 32, L, 1024, Wl, 2048, bl, lab, 2048, blockIdx.x, blockIdx.y, shf);
  } else {
    if (blockIdx.x >= 64) return;
    rgemm8_body(1024, 32, L, 1024, Wsp2T, 1024, nullptr, MmTf, 1024,
                blockIdx.x, blockIdx.y, shf);
  }
}

// ---------- mega1: kmat(fp8 x1024) + BvecB + misc + bt0A(K-parallel) ----------
__global__ __launch_bounds__(256) void mega1_k(
    const float* __restrict__ lab, const float* __restrict__ W1cT,
    unsigned char* __restrict__ KT8,
    const float* __restrict__ W1b, const float* __restrict__ b1,
    float* __restrict__ BvecB,
    const float* __restrict__ bsp2, const float* __restrict__ L,
    float* __restrict__ cv, const float* __restrict__ MmTf,
    unsigned short* __restrict__ MmTb, const float* __restrict__ W2,
    unsigned short* __restrict__ W2padT, const float* __restrict__ bsp1,
    unsigned short* __restrict__ bsp1b,
    const float* __restrict__ bt, const float* __restrict__ W1a,
    float* __restrict__ bt0A) {
  __shared__ float shf[10240];
  int g = blockIdx.x;
  if (g < 8192) {  // KT8[(c*512+d)][h] = fp8(l1[c][h] * W1c[h][d] * 1024)
    size_t gid = (size_t)g * 256 + threadIdx.x;
    int row = (int)(gid >> 7);
    int h0 = ((int)gid & 127) * 8;
    int c = row >> 9, d = row & 511;
    const float* lp = lab + (size_t)c * 2048 + 1024 + h0;
    const float* wp = W1cT + (size_t)d * 1024 + h0;
    float4 l0 = *(const float4*)lp, l1 = *(const float4*)(lp + 4);
    float4 w0 = *(const float4*)wp, w1 = *(const float4*)(wp + 4);
    unsigned u0 = (unsigned)f2e4m3(l0.x * w0.x * 1024.f)
                | ((unsigned)f2e4m3(l0.y * w0.y * 1024.f) << 8)
                | ((unsigned)f2e4m3(l0.z * w0.z * 1024.f) << 16)
                | ((unsigned)f2e4m3(l0.w * w0.w * 1024.f) << 24);
    unsigned u1 = (unsigned)f2e4m3(l1.x * w1.x * 1024.f)
                | ((unsigned)f2e4m3(l1.y * w1.y * 1024.f) << 8)
                | ((unsigned)f2e4m3(l1.z * w1.z * 1024.f) << 16)
                | ((unsigned)f2e4m3(l1.w * w1.w * 1024.f) << 24);
    *(uint2*)(KT8 + (size_t)row * 1024 + h0) = make_uint2(u0, u1);
  } else if (g < 8320) {  // BvecB = l0 @ W1b + b1   (32 x 512)
    int b = g - 8192;
    rgemm8_body(512, 32, lab, 2048, W1b, 512, b1, BvecB, 512, b & 31, b >> 5, shf);
  } else {
    int b = g - 8320;
    if (b < 32) {  // cv[c] = dot(bsp2, L[c])
      int c = b;
      float a = 0.f;
      for (int k = threadIdx.x; k < 1024; k += 256)
        a = fmaf(bsp2[k], L[(size_t)c * 1024 + k], a);
#pragma unroll
      for (int off = 32; off; off >>= 1) a += __shfl_down(a, off);
      if ((threadIdx.x & 63) == 0) shf[threadIdx.x >> 6] = a;
      __syncthreads();
      if (threadIdx.x == 0) cv[c] = shf[0] + shf[1] + shf[2] + shf[3];
    } else if (b < 64) {  // MmTf -> MmTb bf16
      int i = (b - 32) * 1024 + threadIdx.x * 4;
      float4 v = *(const float4*)(MmTf + i);
      *(ushort4*)(MmTb + i) = make_ushort4(f2b(v.x), f2b(v.y), f2b(v.z), f2b(v.w));
    } else if (b < 96) {  // W2padT[n][d] = n<3 ? W2[d][n] : 0
      int i = (b - 64) * 256 + threadIdx.x;
      int n = i >> 9, d = i & 511;
      W2padT[i] = f2b(n < 3 ? W2[d * 3 + n] : 0.f);
    } else if (b == 96) {  // bsp1 -> bsp1b bf16
      int i = threadIdx.x * 4;
      float4 v = *(const float4*)(bsp1 + i);
      *(ushort4*)(bsp1b + i) = make_ushort4(f2b(v.x), f2b(v.y), f2b(v.z), f2b(v.w));
    } else {  // b in [97,129): bt0A[d] = dot(bt[0:1024], W1a[:,d]), K-parallel
      float (*red)[16] = (float(*)[16])shf;
      int tx = threadIdx.x & 15, ty = threadIdx.x >> 4;
      int d = (b - 97) * 16 + tx;
      float a = 0.f;
      for (int k = ty * 64; k < ty * 64 + 64; ++k)
        a = fmaf(bt[k], W1a[(size_t)k * 512 + d], a);
      red[ty][tx] = a;
      __syncthreads();
      if (ty == 0) {
        float s = 0.f;
#pragma unroll
        for (int q = 0; q < 16; ++q) s += red[q][tx];
        bt0A[d] = s;
      }
    }
  }
}

// ---------- wfuse: bf16 GEMM 512x1024, out fp8 x64 (Avec folding matrix) ----------
__global__ __launch_bounds__(256) void wfuse_k(
    const unsigned short* __restrict__ A, const unsigned short* __restrict__ BT,
    unsigned char* __restrict__ out8) {
  __shared__ __align__(16) unsigned short smem[2][16384];
  int tid = threadIdx.x;
  int lane = tid & 63, wid = tid >> 6;
  int wr = wid >> 1, wc = wid & 1;
  int row0 = blockIdx.y * 128, col0 = blockIdx.x * 128;
  f32x4 zero4 = {0.f, 0.f, 0.f, 0.f};
  f32x4 acc[4][4];
#pragma unroll
  for (int i = 0; i < 4; ++i)
#pragma unroll
    for (int j = 0; j < 4; ++j) acc[i][j] = zero4;
  int srow = tid >> 3;
  int scol = ((tid & 7) ^ (srow & 7)) * 8;
  const unsigned short* gA = A + (size_t)(row0 + srow) * 1024 + scol;
  const unsigned short* gB = BT + (size_t)(col0 + srow) * 1024 + scol;
  int fr = lane & 15, hi = lane >> 4;
#define W_STAGE(buf, kt)                                                     \
  {                                                                          \
    unsigned short* dA = smem[buf] + tid * 8;                                \
    unsigned short* dB = smem[buf] + 8192 + tid * 8;                         \
    _Pragma("unroll")                                                        \
    for (int i2 = 0; i2 < 4; ++i2) {                                         \
      GLOAD_LDS16(gA + (size_t)(i2 * 32) * 1024 + (kt), dA + i2 * 2048);     \
      GLOAD_LDS16(gB + (size_t)(i2 * 32) * 1024 + (kt), dB + i2 * 2048);     \
    }                                                                        \
  }
  W_STAGE(0, 0);
  for (int t = 0; t < 16; ++t) {
    if (t + 1 < 16) {
      W_STAGE((t + 1) & 1, (t + 1) << 6);
      asm volatile("s_waitcnt vmcnt(8)" ::: "memory");
    } else {
      asm volatile("s_waitcnt vmcnt(0)" ::: "memory");
    }
    __builtin_amdgcn_sched_barrier(0);
    __builtin_amdgcn_s_barrier();
    __builtin_amdgcn_sched_barrier(0);
    const unsigned short* As = smem[t & 1];
    const unsigned short* Bs = smem[t & 1] + 8192;
    bf16x8 af[4][2], bfr[4][2];
#pragma unroll
    for (int mi = 0; mi < 4; ++mi) {
      int rl = wr * 64 + mi * 16 + fr;
#pragma unroll
      for (int kk = 0; kk < 2; ++kk)
        af[mi][kk] = *(const bf16x8*)&As[rl * 64 + (((kk << 2) | hi) ^ (rl & 7)) * 8];
    }
#pragma unroll
    for (int ni = 0; ni < 4; ++ni) {
      int rl = wc * 64 + ni * 16 + fr;
#pragma unroll
      for (int kk = 0; kk < 2; ++kk)
        bfr[ni][kk] = *(const bf16x8*)&Bs[rl * 64 + (((kk << 2) | hi) ^ (rl & 7)) * 8];
    }
#pragma unroll
    for (int kk = 0; kk < 2; ++kk)
#pragma unroll
      for (int mi = 0; mi < 4; ++mi)
#pragma unroll
        for (int ni = 0; ni < 4; ++ni)
          acc[mi][ni] = __builtin_amdgcn_mfma_f32_16x16x32_bf16(af[mi][kk], bfr[ni][kk],
                                                                acc[mi][ni], 0, 0, 0);
    __builtin_amdgcn_sched_barrier(0);
    __builtin_amdgcn_s_barrier();
  }
#undef W_STAGE
  int rbase = row0 + wr * 64 + (hi << 2);
  int cbase = col0 + wc * 64 + fr;
#pragma unroll
  for (int mi = 0; mi < 4; ++mi)
#pragma unroll
    for (int ni = 0; ni < 4; ++ni) {
      int ccol = cbase + ni * 16;
#pragma unroll
      for (int j = 0; j < 4; ++j) {
        int r = rbase + mi * 16 + j;
        out8[(size_t)r * 1024 + ccol] = f2e4m3(acc[mi][ni][j] * 64.f);
      }
    }
}

// ---------- fgemm: fp8 K=128 merged GEMM [t1 | UV | Avec], N=3584 ----------
// A = we8 (x16), BT = [WtT8;Wsp1Tc8;WfuseT8] (x64); undo 2^-10 in epilogue.
__global__ __launch_bounds__(256) void fgemm_k(
    const unsigned char* __restrict__ A, const unsigned char* __restrict__ BT,
    float* __restrict__ Avec, unsigned char* __restrict__ t1f8,
    unsigned short* __restrict__ UVb,
    const float* __restrict__ bt, const float* __restrict__ bt0A) {
  __shared__ __align__(16) unsigned char smem[2][32768];
  int tid = threadIdx.x;
  int lane = tid & 63, wid = tid >> 6;
  int wr = wid >> 1, wc = wid & 1;
  int row0 = blockIdx.y * 128, col0 = blockIdx.x * 128;
  f32x4 zero4 = {0.f, 0.f, 0.f, 0.f};
  f32x4 acc[4][4];
#pragma unroll
  for (int i = 0; i < 4; ++i)
#pragma unroll
    for (int j = 0; j < 4; ++j) acc[i][j] = zero4;
  // staging: phys slot s holds logical chunk rotl3(s ^ (row&7))
  int srow = tid >> 3;
  int s2 = (tid & 7) ^ (srow & 7);
  int scolB = (((s2 << 1) | (s2 >> 2)) & 7) * 16;
  const unsigned char* gA = A + (size_t)(row0 + srow) * 1024 + scolB;
  const unsigned char* gB = BT + (size_t)(col0 + srow) * 1024 + scolB;
  int fr = lane & 15, hi = lane >> 4;
#define F_STAGE(buf, ktB)                                                    \
  {                                                                          \
    unsigned char* dA = smem[buf] + tid * 16;                                \
    unsigned char* dB = smem[buf] + 16384 + tid * 16;                        \
    _Pragma("unroll")                                                        \
    for (int i2 = 0; i2 < 4; ++i2) {                                         \
      GLOAD_LDS16(gA + (size_t)(i2 * 32) * 1024 + (ktB), dA + i2 * 4096);    \
      GLOAD_LDS16(gB + (size_t)(i2 * 32) * 1024 + (ktB), dB + i2 * 4096);    \
    }                                                                        \
  }
  F_STAGE(0, 0);
  for (int t = 0; t < 8; ++t) {
    if (t + 1 < 8) {
      F_STAGE((t + 1) & 1, (t + 1) * 128);
      asm volatile("s_waitcnt vmcnt(8)" ::: "memory");
    } else {
      asm volatile("s_waitcnt vmcnt(0)" ::: "memory");
    }
    __builtin_amdgcn_sched_barrier(0);
    __builtin_amdgcn_s_barrier();
    __builtin_amdgcn_sched_barrier(0);
    const unsigned char* As = smem[t & 1];
    const unsigned char* Bs = smem[t & 1] + 16384;
    i32x8 af[4], bfr[4];
#pragma unroll
    for (int mi = 0; mi < 4; ++mi) {
      int rl = wr * 64 + mi * 16 + fr;
      i32x4 lo = *(const i32x4*)&As[rl * 128 + ((hi ^ (rl & 7)) * 16)];
      i32x4 h2 = *(const i32x4*)&As[rl * 128 + (((4 + hi) ^ (rl & 7)) * 16)];
      af[mi][0] = lo[0]; af[mi][1] = lo[1]; af[mi][2] = lo[2]; af[mi][3] = lo[3];
      af[mi][4] = h2[0]; af[mi][5] = h2[1]; af[mi][6] = h2[2]; af[mi][7] = h2[3];
    }
#pragma unroll
    for (int ni = 0; ni < 4; ++ni) {
      int rl = wc * 64 + ni * 16 + fr;
      i32x4 lo = *(const i32x4*)&Bs[rl * 128 + ((hi ^ (rl & 7)) * 16)];
      i32x4 h2 = *(const i32x4*)&Bs[rl * 128 + (((4 + hi) ^ (rl & 7)) * 16)];
      bfr[ni][0] = lo[0]; bfr[ni][1] = lo[1]; bfr[ni][2] = lo[2]; bfr[ni][3] = lo[3];
      bfr[ni][4] = h2[0]; bfr[ni][5] = h2[1]; bfr[ni][6] = h2[2]; bfr[ni][7] = h2[3];
    }
#pragma unroll
    for (int mi = 0; mi < 4; ++mi)
#pragma unroll
      for (int ni = 0; ni < 4; ++ni)
        acc[mi][ni] = __builtin_amdgcn_mfma_scale_f32_16x16x128_f8f6f4(
            af[mi], bfr[ni], acc[mi][ni], 0, 0, 0, 127u, 0, 127u);
    __builtin_amdgcn_sched_barrier(0);
    __builtin_amdgcn_s_barrier();
  }
#undef F_STAGE
  const float inv = 0.0009765625f;  // 2^-10 (16 * 64)
  int rbase = row0 + wr * 64 + (hi << 2);
  int cbase = col0 + wc * 64 + fr;
#pragma unroll
  for (int mi = 0; mi < 4; ++mi)
#pragma unroll
    for (int ni = 0; ni < 4; ++ni) {
      int ccol = cbase + ni * 16;
#pragma unroll
      for (int j = 0; j < 4; ++j) {
        int r = rbase + mi * 16 + j;
        float v = acc[mi][ni][j] * inv;
        if (ccol < 1024) {
          t1f8[(size_t)r * 1024 + ccol] = f2e4m3((v + bt[1024 + ccol]) * 16.f);
        } else if (ccol < 3072) {
          UVb[(size_t)r * 2048 + (ccol - 1024)] = f2b(v);
        } else {
          Avec[(size_t)r * 512 + (ccol - 3072)] = v + bt0A[ccol - 3072];
        }
      }
    }
}

// ---------- E-GEMM: 128² tile, MX-fp8 K=128, rotl3 chunk swizzle, supertile ----------
__global__ __launch_bounds__(256) void egemm_k(
    const unsigned char* __restrict__ A,   // t1f8 (x16)
    const unsigned char* __restrict__ BT,  // KT8 (x1024)
    const float* __restrict__ avec, const float* __restrict__ bvec,
    const unsigned short* __restrict__ w2t, float* __restrict__ sPart) {
  __shared__ __align__(16) unsigned char smem[2][32768];
  int tid = threadIdx.x;
  int lane = tid & 63, wid = tid >> 6;
  int wr = wid >> 1, wc = wid & 1;
  int bid = blockIdx.x;
  int xcd = bid & 7, ii = bid >> 3;
  int sg = ii >> 6, inner = ii & 63;
  int rb = ((sg >> 1) << 3) | (inner & 7);
  int cb = xcd * 16 + (((sg & 1) << 3) | (inner >> 3));
  int row0 = rb * 128, col0 = cb * 128, cbq = cb & 3;

  f32x4 zero4 = {0.f, 0.f, 0.f, 0.f};
  f32x4 acc[4][4];
#pragma unroll
  for (int i = 0; i < 4; ++i)
#pragma unroll
    for (int j = 0; j < 4; ++j) acc[i][j] = zero4;

  int srow = tid >> 3;
  int s2 = (tid & 7) ^ (srow & 7);
  int scolB = (((s2 << 1) | (s2 >> 2)) & 7) * 16;
  const unsigned char* gA = A + (size_t)(row0 + srow) * 1024 + scolB;
  const unsigned char* gB = BT + (size_t)(col0 + srow) * 1024 + scolB;

  int fr = lane & 15, hi = lane >> 4;

#define E_STAGE(buf, ktB)                                                    \
  {                                                                          \
    unsigned char* dA = smem[buf] + tid * 16;                                \
    unsigned char* dB = smem[buf] + 16384 + tid * 16;                        \
    _Pragma("unroll")                                                        \
    for (int i2 = 0; i2 < 4; ++i2) {                                         \
      GLOAD_LDS16(gA + (size_t)(i2 * 32) * 1024 + (ktB), dA + i2 * 4096);    \
      GLOAD_LDS16(gB + (size_t)(i2 * 32) * 1024 + (ktB), dB + i2 * 4096);    \
    }                                                                        \
  }

  E_STAGE(0, 0);

  for (int t = 0; t < 8; ++t) {
    if (t + 1 < 8) {
      E_STAGE((t + 1) & 1, (t + 1) * 128);
      asm volatile("s_waitcnt vmcnt(8)" ::: "memory");
    } else {
      asm volatile("s_waitcnt vmcnt(0)" ::: "memory");
    }
    __builtin_amdgcn_sched_barrier(0);
    __builtin_amdgcn_s_barrier();
    __builtin_amdgcn_sched_barrier(0);

    const unsigned char* As = smem[t & 1];
    const unsigned char* Bs = smem[t & 1] + 16384;
    i32x8 af[4], bfr[4];
#pragma unroll
    for (int mi = 0; mi < 4; ++mi) {
      int rl = wr * 64 + mi * 16 + fr;
      i32x4 lo = *(const i32x4*)&As[rl * 128 + ((hi ^ (rl & 7)) * 16)];
      i32x4 h2 = *(const i32x4*)&As[rl * 128 + (((4 + hi) ^ (rl & 7)) * 16)];
      af[mi][0] = lo[0]; af[mi][1] = lo[1]; af[mi][2] = lo[2]; af[mi][3] = lo[3];
      af[mi][4] = h2[0]; af[mi][5] = h2[1]; af[mi][6] = h2[2]; af[mi][7] = h2[3];
    }
#pragma unroll
    for (int ni = 0; ni < 4; ++ni) {
      int rl = wc * 64 + ni * 16 + fr;
      i32x4 lo = *(const i32x4*)&Bs[rl * 128 + ((hi ^ (rl & 7)) * 16)];
      i32x4 h2 = *(const i32x4*)&Bs[rl * 128 + (((4 + hi) ^ (rl & 7)) * 16)];
      bfr[ni][0] = lo[0]; bfr[ni][1] = lo[1]; bfr[ni][2] = lo[2]; bfr[ni][3] = lo[3];
      bfr[ni][4] = h2[0]; bfr[ni][5] = h2[1]; bfr[ni][6] = h2[2]; bfr[ni][7] = h2[3];
    }
#pragma unroll
    for (int mi = 0; mi < 4; ++mi)
#pragma unroll
      for (int ni = 0; ni < 4; ++ni)
        acc[mi][ni] = __builtin_amdgcn_mfma_scale_f32_16x16x128_f8f6f4(
            af[mi], bfr[ni], acc[mi][ni], 0, 0, 0, 127u, 0, 127u);
    __builtin_amdgcn_sched_barrier(0);
    __builtin_amdgcn_s_barrier();
  }
#undef E_STAGE

  // ---- epilogue: h -> swizzled LDS -> W2 MFMA ----
  unsigned short* hsm = (unsigned short*)&smem[0][0];
  int cc = col0 >> 9;
  int dg0 = col0 & 511;
  const float inv = 6.103515625e-05f;  // 2^-14 (16 * 1024)
#pragma unroll
  for (int mi = 0; mi < 4; ++mi) {
#pragma unroll
    for (int j = 0; j < 4; ++j) {
      int rl = wr * 64 + hi * 4 + mi * 16 + j;
      const float* avp = avec + (size_t)(row0 + rl) * 512 + dg0;
      const float* bvp = bvec + (size_t)cc * 512 + dg0;
#pragma unroll
      for (int ni = 0; ni < 4; ++ni) {
        int cl = wc * 64 + ni * 16 + fr;
        float v = acc[mi][ni][j] * inv + avp[cl] + bvp[cl];
        v = fmaxf(v, 0.f);
        int slot = cl >> 3;
        hsm[rl * 128 + (((slot ^ rl) & 7) << 3) + (slot & 8) * 8 + (cl & 7)] = f2b(v);
      }
    }
  }
  __syncthreads();
  f32x4 s0 = zero4, s1 = zero4;
  int r0l = wid * 32 + fr;
  int r1l = wid * 32 + 16 + fr;
#pragma unroll
  for (int kt2 = 0; kt2 < 4; ++kt2) {
    int slot = kt2 * 4 + hi;
    bf16x8 a0 = *(const bf16x8*)&hsm[r0l * 128 + (((slot ^ r0l) & 7) << 3) + (slot & 8) * 8];
    bf16x8 a1 = *(const bf16x8*)&hsm[r1l * 128 + (((slot ^ r1l) & 7) << 3) + (slot & 8) * 8];
    bf16x8 b = *(const bf16x8*)&w2t[(size_t)fr * 512 + dg0 + kt2 * 32 + hi * 8];
    s0 = __builtin_amdgcn_mfma_f32_16x16x32_bf16(a0, b, s0, 0, 0, 0);
    s1 = __builtin_amdgcn_mfma_f32_16x16x32_bf16(a1, b, s1, 0, 0, 0);
  }
  if (fr < 3) {
    float* sp = sPart + ((size_t)cbq * 2048 + row0) * 96 + cc * 3 + fr;
#pragma unroll
    for (int j = 0; j < 4; ++j) {
      sp[(size_t)(wid * 32 + hi * 4 + j) * 96] = s0[j];
      sp[(size_t)(wid * 32 + 16 + hi * 4 + j) * 96] = s1[j];
    }
  }
}

// ---------- fold 4 score slices + b2, then is_start/is_end ----------
__global__ __launch_bounds__(256) void foldmask_k(const float* __restrict__ part,
    const float* __restrict__ b2, float* __restrict__ outS,
    int* __restrict__ is_s, int* __restrict__ is_e) {
  __shared__ float sc[192];
  int b = blockIdx.x;
  int i = threadIdx.x;
  if (i < 192) {
    int idx = b * 192 + i;
    float s = b2[i % 3] + part[idx] + part[196608 + idx] +
              part[2 * 196608 + idx] + part[3 * 196608 + idx];
    outS[idx] = s;
    sc[i] = s;
  }
  __syncthreads();
  if (i < 2) {
    int s = 0, e = 0;
#pragma unroll
    for (int c = 0; c < 32; ++c) {
      s |= (sc[i * 96 + c * 3 + 0] >= 0.f);
      e |= (sc[i * 96 + c * 3 + 1] >= 0.f);
    }
    is_s[2 * b + i] = s;
    is_e[2 * b + i] = e;
  }
}

// ---------- fused span: 16 spans/wave, barrier-free, 2-step unrolled ----------
__global__ __launch_bounds__(256) void spanfuse_k(
    const unsigned short* __restrict__ UVb, const unsigned short* __restrict__ bsp1b,
    const unsigned short* __restrict__ MmTb, const float* __restrict__ cvv,
    const int* __restrict__ is_s, const int* __restrict__ is_e,
    float* __restrict__ outIdx, float* __restrict__ outMask,
    float* __restrict__ outLog) {
  __shared__ __align__(16) unsigned short Rs[4][2][16][32];  // 8 KB
  int tid = threadIdx.x, lane = tid & 63, w = tid >> 6;
  int fr = lane & 15, hi = lane >> 4;
  int row = lane >> 2, q = lane & 3;
  int n = blockIdx.x * 64 + w * 16 + row;
  int wi = n / MAXW;
  int j = n - wi * MAXW;
  int er = wi + j;
  int valid = er < W_WORDS;
  int e = valid ? er : (W_WORDS - 1);
  int mask = (valid && is_s[wi] && is_e[e]) ? 1 : 0;
  if (q == 0) {
    outIdx[2 * n] = (float)wi;
    outIdx[2 * n + 1] = (float)e;
    outMask[n] = (float)mask;
  }
  int si = mask ? wi : 0, ei = mask ? e : 0;
  const unsigned short* Up = UVb + (size_t)si * 2048 + q * 8;
  const unsigned short* Vp = UVb + (size_t)ei * 2048 + 1024 + q * 8;
  const unsigned short* bp = bsp1b + q * 8;
  const unsigned short* M0 = MmTb + (size_t)fr * 1024 + hi * 8;
  const unsigned short* M1 = MmTb + (size_t)(16 + fr) * 1024 + hi * 8;
  unsigned short* wRs0 = &Rs[w][0][0][0];
  unsigned short* wRs1 = &Rs[w][1][0][0];
  int wslot = (q ^ (row & 3)) * 8;
  int rslot = ((hi ^ (fr & 3)) & 3) * 8;
  f32x4 zero4 = {0.f, 0.f, 0.f, 0.f};
  f32x4 a0 = zero4, a1 = zero4;

  bf16x8 u0 = *(const bf16x8*)Up,        v0 = *(const bf16x8*)Vp;
  bf16x8 b0 = *(const bf16x8*)bp;
  bf16x8 u1 = *(const bf16x8*)(Up + 32), v1 = *(const bf16x8*)(Vp + 32);
  bf16x8 b1v = *(const bf16x8*)(bp + 32);
  bf16x8 f00 = *(const bf16x8*)M0,        f10 = *(const bf16x8*)M1;
  bf16x8 f01 = *(const bf16x8*)(M0 + 32), f11 = *(const bf16x8*)(M1 + 32);

  for (int kt = 0; kt < 32; kt += 2) {
    int ka = ((kt + 2) & 31) * 32, kb = ((kt + 3) & 31) * 32;
    bf16x8 nu0 = *(const bf16x8*)(Up + ka), nv0 = *(const bf16x8*)(Vp + ka);
    bf16x8 nb0 = *(const bf16x8*)(bp + ka);
    bf16x8 nu1 = *(const bf16x8*)(Up + kb), nv1 = *(const bf16x8*)(Vp + kb);
    bf16x8 nb1 = *(const bf16x8*)(bp + kb);
    bf16x8 nf00 = *(const bf16x8*)(M0 + ka), nf10 = *(const bf16x8*)(M1 + ka);
    bf16x8 nf01 = *(const bf16x8*)(M0 + kb), nf11 = *(const bf16x8*)(M1 + kb);

    bf16x8 o0, o1;
#pragma unroll
    for (int i = 0; i < 8; ++i) {
      o0[i] = (short)f2b(fmaxf(b2f((unsigned short)u0[i]) + b2f((unsigned short)v0[i]) +
                               b2f((unsigned short)b0[i]), 0.f));
      o1[i] = (short)f2b(fmaxf(b2f((unsigned short)u1[i]) + b2f((unsigned short)v1[i]) +
                               b2f((unsigned short)b1v[i]), 0.f));
    }
    *(bf16x8*)&wRs0[row * 32 + wslot] = o0;
    *(bf16x8*)&wRs1[row * 32 + wslot] = o1;
    asm volatile("s_waitcnt lgkmcnt(0)" ::: "memory");
    bf16x8 fa0 = *(const bf16x8*)&wRs0[fr * 32 + rslot];
    bf16x8 fa1 = *(const bf16x8*)&wRs1[fr * 32 + rslot];
    a0 = __builtin_amdgcn_mfma_f32_16x16x32_bf16(fa0, f00, a0, 0, 0, 0);
    a1 = __builtin_amdgcn_mfma_f32_16x16x32_bf16(fa0, f10, a1, 0, 0, 0);
    a0 = __builtin_amdgcn_mfma_f32_16x16x32_bf16(fa1, f01, a0, 0, 0, 0);
    a1 = __builtin_amdgcn_mfma_f32_16x16x32_bf16(fa1, f11, a1, 0, 0, 0);
    u0 = nu0; v0 = nv0; b0 = nb0;
    u1 = nu1; v1 = nv1; b1v = nb1;
    f00 = nf00; f10 = nf10; f01 = nf01; f11 = nf11;
  }

  int n0 = blockIdx.x * 64 + w * 16;
  float c0 = cvv[fr], c1 = cvv[16 + fr];
#pragma unroll
  for (int jj = 0; jj < 4; ++jj) {
    int nn = n0 + hi * 4 + jj;
    outLog[(size_t)nn * 32 + fr] = a0[jj] + c0;
    outLog[(size_t)nn * 32 + 16 + fr] = a1[jj] + c1;
  }
}

extern "C" void kernel_launch(void* const* d_in, const int* in_sizes, int n_in,
                              void* d_out, int out_size, void* d_ws, size_t ws_size,
                              hipStream_t stream) {
  const float* hs   = (const float*)d_in[0];
  const int*   wm   = (const int*)d_in[1];
  const float* L    = (const float*)d_in[2];
  const float* Wt   = (const float*)d_in[3];
  const float* bt   = (const float*)d_in[4];
  const float* Wl   = (const float*)d_in[5];
  const float* bl   = (const float*)d_in[6];
  const float* W1a  = (const float*)d_in[7];
  const float* W1b  = (const float*)d_in[8];
  const float* W1c  = (const float*)d_in[9];
  const float* b1   = (const float*)d_in[10];
  const float* W2   = (const float*)d_in[11];
  const float* b2   = (const float*)d_in[12];
  const float* Wsp1 = (const float*)d_in[13];
  const float* bsp1 = (const float*)d_in[14];
  const float* Wsp2 = (const float*)d_in[15];
  const float* bsp2 = (const float*)d_in[16];

  char* p = (char*)d_ws;
  auto alloc = [&p](size_t bytes) {
    char* r = p;
    p += (bytes + 255) & ~(size_t)255;
    return r;
  };
  unsigned char*  we8    = (unsigned char*)alloc((size_t)2048 * 1024);
  // WtT8, Wsp1Tc8, WfuseT8 MUST be adjacent: merged BT (3584 x 1024 fp8)
  unsigned char*  WtT8    = (unsigned char*)alloc((size_t)1024 * 1024);
  unsigned char*  Wsp1Tc8 = (unsigned char*)alloc((size_t)2048 * 1024);
  unsigned char*  WfuseT8 = (unsigned char*)alloc((size_t)512 * 1024);
  unsigned char*  t1f8   = (unsigned char*)alloc((size_t)2048 * 1024);
  float*          lab    = (float*)alloc((size_t)32 * 2048 * 4);
  unsigned short* W1aT   = (unsigned short*)alloc((size_t)512 * 1024 * 2);
  unsigned short* Wtb0   = (unsigned short*)alloc((size_t)1024 * 1024 * 2);
  float*          Avec   = (float*)alloc((size_t)2048 * 512 * 4);
  float*          BvecB  = (float*)alloc((size_t)32 * 512 * 4);
  float*          bt0A   = (float*)alloc(512 * 4);
  float*          W1cT   = (float*)alloc((size_t)512 * 1024 * 4);
  unsigned char*  KT8    = (unsigned char*)alloc((size_t)16384 * 1024);
  float*          sPart  = (float*)alloc((size_t)4 * 2048 * 96 * 4);
  int*            is_s   = (int*)alloc(2048 * 4);
  int*            is_e   = (int*)alloc(2048 * 4);
  unsigned short* UVb    = (unsigned short*)alloc((size_t)2048 * 2048 * 2);
  float*          Wsp2T  = (float*)alloc((size_t)1024 * 1024 * 4);
  float*          MmTf   = (float*)alloc((size_t)32 * 1024 * 4);
  unsigned short* MmTb   = (unsigned short*)alloc((size_t)32 * 1024 * 2);
  float*          cv     = (float*)alloc(32 * 4);
  unsigned short* W2padT = (unsigned short*)alloc((size_t)16 * 512 * 2);
  unsigned short* bsp1b  = (unsigned short*)alloc((size_t)1024 * 2);

  float* outS    = (float*)d_out;
  float* outIdx  = outS + (size_t)2048 * 32 * 3;
  float* outMask = outIdx + (size_t)NSPAN * 2;
  float* outLog  = outMask + NSPAN;

  // transposes (fp8 weights) + gather (fp8 we) + Wtb0 in one launch
  mega0_k<<<dim3(96, 32, 8), dim3(32, 8), 0, stream>>>(
      hs, wm, we8, Wt, W1a, Wsp1, W1c, Wsp2, WtT8, W1aT, Wsp1Tc8, W1cT, Wsp2T, Wtb0);

  // lab = L@Wl+bl and MmTf = L@Wsp2T
  rgemm8z_k<<<dim3(128, 4, 2), 256, 0, stream>>>(L, Wl, bl, lab, Wsp2T, MmTf);

  // kmat(fp8) + BvecB + misc + bt0A in one launch
  mega1_k<<<8449, 256, 0, stream>>>(lab, W1cT, KT8, W1b, b1, BvecB,
                                    bsp2, L, cv, MmTf, MmTb, W2, W2padT, bsp1, bsp1b,
                                    bt, W1a, bt0A);

  // WfuseT8 = fp8(x64) of W1aT @ Wtb0^T  (512 x 1024)
  wfuse_k<<<dim3(8, 4), 256, 0, stream>>>(W1aT, Wtb0, WfuseT8);

  // merged fp8: [t1 | UV | Avec] = we @ [Wt_hi | Wsp1 | Wfuse]  (N = 3584)
  fgemm_k<<<dim3(28, 16), 256, 0, stream>>>(we8, WtT8, Avec, t1f8, UVb, bt, bt0A);

  // E-GEMM (MX-fp8 K=128, rotl3 swizzle, supertile) + fused score partials
  egemm_k<<<2048, 256, 0, stream>>>(t1f8, KT8, Avec, BvecB, W2padT, sPart);

  // fold scores + masks
  foldmask_k<<<1024, 256, 0, stream>>>(sPart, b2, outS, is_s, is_e);

  // fused span: 16 spans/wave, barrier-free, 2-step unrolled
  spanfuse_k<<<384, 256, 0, stream>>>(UVb, bsp1b, MmTb, cv, is_s, is_e,
                                      outIdx, outMask, outLog);
}